// Round 1
// baseline (1581.578 us; speedup 1.0000x reference)
//
#include <hip/hip_runtime.h>

#define N_TOK 2048
#define N_CLU 256
#define N_ALL 2304
#define DMODEL 512
#define NH 16
#define HD 32
#define BATCH 2

__device__ __forceinline__ float rscale() { return 0.17677669529663687f; } // 32^-0.5

// ---------------- Generic fp32 GEMM: C[M,N] = A[M,K] @ B[K,N] ----------------
// tile 128x64, Ktile 16, 256 threads, 8x4 per thread. M = gridDim.y*128 exactly.
__global__ __launch_bounds__(256) void gemm_f32(
    const float* __restrict__ A, long strideA,
    const float* __restrict__ B,
    float* __restrict__ C, long strideC,
    int N, int K)
{
    A += (long)blockIdx.z * strideA;
    C += (long)blockIdx.z * strideC;
    const int m0 = blockIdx.y * 128, n0 = blockIdx.x * 64;
    __shared__ float As[16][128];
    __shared__ float Bs[16][64];
    const int t = threadIdx.x;
    const int tx = t & 15, ty = t >> 4;
    float acc[8][4] = {};
    for (int k0 = 0; k0 < K; k0 += 16) {
        // A tile: 128x16 = 512 float4, 2 per thread (transpose to [k][m])
        #pragma unroll
        for (int i = 0; i < 2; i++) {
            int idx = t + 256 * i;
            int row = idx >> 2;
            int kf  = (idx & 3) * 4;
            float4 av = *(const float4*)&A[(long)(m0 + row) * K + k0 + kf];
            As[kf + 0][row] = av.x; As[kf + 1][row] = av.y;
            As[kf + 2][row] = av.z; As[kf + 3][row] = av.w;
        }
        // B tile: 16x64 = 256 float4, 1 per thread
        {
            int kk = t >> 4, nf = (t & 15) * 4;
            *(float4*)&Bs[kk][nf] = *(const float4*)&B[(long)(k0 + kk) * N + n0 + nf];
        }
        __syncthreads();
        #pragma unroll
        for (int kk = 0; kk < 16; kk++) {
            float a[8], bb[4];
            #pragma unroll
            for (int i = 0; i < 8; i++) a[i] = As[kk][ty * 8 + i];
            #pragma unroll
            for (int j = 0; j < 4; j++) bb[j] = Bs[kk][tx * 4 + j];
            #pragma unroll
            for (int i = 0; i < 8; i++)
                #pragma unroll
                for (int j = 0; j < 4; j++)
                    acc[i][j] += a[i] * bb[j];
        }
        __syncthreads();
    }
    #pragma unroll
    for (int i = 0; i < 8; i++) {
        float4 v = { acc[i][0], acc[i][1], acc[i][2], acc[i][3] };
        *(float4*)&C[(long)(m0 + ty * 8 + i) * N + n0 + tx * 4] = v;
    }
}

// ---------------- Token-query attention (softmax over keys, streaming) -------
// grid (8,16,2), 256 threads; thread = one query row of one (b,h).
__global__ __launch_bounds__(256) void attn_x_kernel(
    const float* __restrict__ q,    // (b, 2304, 512)
    const float* __restrict__ kv,   // (b, 2048, 1024)
    float* __restrict__ ao)         // (b, 2304, 512)
{
    const int b = blockIdx.z, h = blockIdx.y;
    const int q0 = blockIdx.x * 256;
    const int t = threadIdx.x;
    __shared__ float Ks[64][32];
    __shared__ float Vs[64][32];
    const float* qrow = q + ((long)b * N_ALL + q0 + t) * DMODEL + h * HD;
    float qr[32];
    #pragma unroll
    for (int e = 0; e < 32; e++) qr[e] = qrow[e] * rscale();
    float acc[32] = {};
    float l = 0.f;
    const float* kvb = kv + (long)b * N_TOK * (2 * DMODEL) + h * HD;
    for (int k0 = 0; k0 < N_TOK; k0 += 64) {
        __syncthreads();
        #pragma unroll
        for (int i = 0; i < 2; i++) {
            int idx = t + 256 * i;           // 0..511
            int row = idx >> 3;
            int e4  = (idx & 7) * 4;
            *(float4*)&Ks[row][e4] = *(const float4*)&kvb[(long)(k0 + row) * (2 * DMODEL) + e4];
            *(float4*)&Vs[row][e4] = *(const float4*)&kvb[(long)(k0 + row) * (2 * DMODEL) + DMODEL + e4];
        }
        __syncthreads();
        #pragma unroll 4
        for (int kk = 0; kk < 64; kk++) {
            float s = 0.f;
            #pragma unroll
            for (int e = 0; e < 32; e++) s += qr[e] * Ks[kk][e];
            float p = __expf(s);             // logits tiny: no max needed
            l += p;
            #pragma unroll
            for (int e = 0; e < 32; e++) acc[e] += p * Vs[kk][e];
        }
    }
    float inv = 1.f / l;
    float* orow = ao + ((long)b * N_ALL + q0 + t) * DMODEL + h * HD;
    #pragma unroll
    for (int e = 0; e < 8; e++) {
        float4 v = { acc[e*4] * inv, acc[e*4+1] * inv, acc[e*4+2] * inv, acc[e*4+3] * inv };
        *(float4*)&orow[e * 4] = v;
    }
}

// ---------------- Cluster path pass 1: per-key column sums -------------------
// grid (8,16,2), 256 threads; thread = one key.
__global__ __launch_bounds__(256) void attn_c_colsum(
    const float* __restrict__ q,
    const float* __restrict__ kv,
    float* __restrict__ invcolsum)  // (b,h,2048)
{
    const int b = blockIdx.z, h = blockIdx.y, k0 = blockIdx.x * 256;
    const int t = threadIdx.x;
    __shared__ float Qc[256][32];   // all 256 cluster-q rows for this head
    #pragma unroll
    for (int i = 0; i < 8; i++) {
        int idx = t + 256 * i;      // 0..2047
        int row = idx >> 3;
        int e4  = (idx & 7) * 4;
        *(float4*)&Qc[row][e4] = *(const float4*)&q[((long)b * N_ALL + N_TOK + row) * DMODEL + h * HD + e4];
    }
    __syncthreads();
    const float* krow = kv + ((long)b * N_TOK + k0 + t) * (2 * DMODEL) + h * HD;
    float kr[32];
    #pragma unroll
    for (int e = 0; e < 32; e++) kr[e] = krow[e] * rscale();
    float sum = 0.f;
    for (int c = 0; c < 256; c++) {
        float s = 0.f;
        #pragma unroll
        for (int e = 0; e < 32; e++) s += kr[e] * Qc[c][e];
        sum += __expf(s);
    }
    invcolsum[((long)b * NH + h) * N_TOK + k0 + t] = 1.f / sum;
}

// ---------------- Cluster path pass 2: fused rowsum + PV (key-split 8) -------
// grid (8,16,2), 256 threads; thread = cluster c, block handles 256 keys.
__global__ __launch_bounds__(256) void attn_c_pv(
    const float* __restrict__ q,
    const float* __restrict__ kv,
    const float* __restrict__ invcolsum,
    float* __restrict__ part)       // (b,h,8,256,33)
{
    const int b = blockIdx.z, h = blockIdx.y, k0 = blockIdx.x * 256;
    const int t = threadIdx.x;      // cluster index
    __shared__ float Ks[64][32];
    __shared__ float Vs[64][32];
    __shared__ float cs[64];
    const float* qrow = q + ((long)b * N_ALL + N_TOK + t) * DMODEL + h * HD;
    float qr[32];
    #pragma unroll
    for (int e = 0; e < 32; e++) qr[e] = qrow[e] * rscale();
    float acc[32] = {};
    float rs = 0.f;
    const float* kvb = kv + (long)b * N_TOK * (2 * DMODEL) + h * HD;
    const float* icb = invcolsum + ((long)b * NH + h) * N_TOK;
    for (int kk0 = 0; kk0 < 256; kk0 += 64) {
        __syncthreads();
        #pragma unroll
        for (int i = 0; i < 2; i++) {
            int idx = t + 256 * i;
            int row = idx >> 3;
            int e4  = (idx & 7) * 4;
            *(float4*)&Ks[row][e4] = *(const float4*)&kvb[(long)(k0 + kk0 + row) * (2 * DMODEL) + e4];
            *(float4*)&Vs[row][e4] = *(const float4*)&kvb[(long)(k0 + kk0 + row) * (2 * DMODEL) + DMODEL + e4];
        }
        if (t < 64) cs[t] = icb[k0 + kk0 + t];
        __syncthreads();
        #pragma unroll 4
        for (int kk = 0; kk < 64; kk++) {
            float s = 0.f;
            #pragma unroll
            for (int e = 0; e < 32; e++) s += qr[e] * Ks[kk][e];
            float p = __expf(s) * cs[kk];
            rs += p;
            #pragma unroll
            for (int e = 0; e < 32; e++) acc[e] += p * Vs[kk][e];
        }
    }
    float* pp = part + ((((long)b * NH + h) * 8 + blockIdx.x) * 256 + t) * 33;
    #pragma unroll
    for (int e = 0; e < 32; e++) pp[e] = acc[e];
    pp[32] = rs;
}

// ---------------- Cluster path reduce: combine key-split partials ------------
__global__ __launch_bounds__(256) void attn_c_reduce(
    const float* __restrict__ part,
    float* __restrict__ ao)
{
    const int gid = blockIdx.x * 256 + threadIdx.x;  // 0..8191
    const int b = gid >> 12, h = (gid >> 8) & 15, c = gid & 255;
    float acc[32] = {};
    float rs = 0.f;
    for (int j = 0; j < 8; j++) {
        const float* pp = part + ((((long)b * NH + h) * 8 + j) * 256 + c) * 33;
        #pragma unroll
        for (int e = 0; e < 32; e++) acc[e] += pp[e];
        rs += pp[32];
    }
    const float inv = 1.f / (rs + 1e-5f);
    float* orow = ao + ((long)b * N_ALL + N_TOK + c) * DMODEL + h * HD;
    #pragma unroll
    for (int e = 0; e < 32; e++) orow[e] = acc[e] * inv;
}

extern "C" void kernel_launch(void* const* d_in, const int* in_sizes, int n_in,
                              void* d_out, int out_size, void* d_ws, size_t ws_size,
                              hipStream_t stream)
{
    const float* x        = (const float*)d_in[0];
    const float* clusters = (const float*)d_in[1];
    // d_in[2] token_sizes: dead input (per-row constant under softmax over k)
    const float* Wq  = (const float*)d_in[3];
    const float* Wkv = (const float*)d_in[4];
    const float* Wo  = (const float*)d_in[5];
    float* out = (float*)d_out;

    float* q    = (float*)d_ws;                          // 2*2304*512
    float* kv   = q   + (long)BATCH * N_ALL * DMODEL;    // 2*2048*1024
    float* ao   = kv  + (long)BATCH * N_TOK * 2 * DMODEL;// 2*2304*512
    float* ics  = ao  + (long)BATCH * N_ALL * DMODEL;    // 2*16*2048
    float* part = ics + (long)BATCH * NH * N_TOK;        // 2*16*8*256*33

    // q_x = x @ Wq  -> q rows [0,2048)
    gemm_f32<<<dim3(DMODEL/64, N_TOK/128, BATCH), 256, 0, stream>>>(
        x, (long)N_TOK*DMODEL, Wq, q, (long)N_ALL*DMODEL, DMODEL, DMODEL);
    // q_c = clusters @ Wq -> q rows [2048,2304)
    gemm_f32<<<dim3(DMODEL/64, N_CLU/128, BATCH), 256, 0, stream>>>(
        clusters, (long)N_CLU*DMODEL, Wq, q + (long)N_TOK*DMODEL, (long)N_ALL*DMODEL, DMODEL, DMODEL);
    // kv = x @ Wkv
    gemm_f32<<<dim3((2*DMODEL)/64, N_TOK/128, BATCH), 256, 0, stream>>>(
        x, (long)N_TOK*DMODEL, Wkv, kv, (long)N_TOK*2*DMODEL, 2*DMODEL, DMODEL);

    // cluster path
    attn_c_colsum<<<dim3(N_TOK/256, NH, BATCH), 256, 0, stream>>>(q, kv, ics);
    attn_c_pv<<<dim3(N_TOK/256, NH, BATCH), 256, 0, stream>>>(q, kv, ics, part);
    attn_c_reduce<<<dim3((BATCH*NH*N_CLU)/256), 256, 0, stream>>>(part, ao);

    // token path
    attn_x_kernel<<<dim3(N_TOK/256, NH, BATCH), 256, 0, stream>>>(q, kv, ao);

    // output projections (straight into d_out)
    gemm_f32<<<dim3(DMODEL/64, N_TOK/128, BATCH), 256, 0, stream>>>(
        ao, (long)N_ALL*DMODEL, Wo, out, (long)N_TOK*DMODEL, DMODEL, DMODEL);
    gemm_f32<<<dim3(DMODEL/64, N_CLU/128, BATCH), 256, 0, stream>>>(
        ao + (long)N_TOK*DMODEL, (long)N_ALL*DMODEL, Wo,
        out + (long)BATCH*N_TOK*DMODEL, (long)N_CLU*DMODEL, DMODEL, DMODEL);
}

// Round 3
// 487.196 us; speedup vs baseline: 3.2463x; 3.2463x over previous
//
#include <hip/hip_runtime.h>
#include <hip/hip_bf16.h>

#define N_TOK 2048
#define N_CLU 256
#define N_ALL 2304
#define DMODEL 512
#define NH 16
#define HD 32
#define BATCH 2
#define SCALE 0.17677669529663687f

typedef short bf16x8 __attribute__((ext_vector_type(8)));
typedef float f32x4  __attribute__((ext_vector_type(4)));

static __device__ __forceinline__ unsigned short f2b(float x) {
    __hip_bfloat16 h = __float2bfloat16(x);
    return *reinterpret_cast<unsigned short*>(&h);
}

// ---------------- fp32 GEMM: C[M,N] = A[M,K] @ B[K,N] (fp32 out) -------------
__global__ __launch_bounds__(256) void gemm_f32(
    const float* __restrict__ A, long strideA,
    const float* __restrict__ B,
    float* __restrict__ C, long strideC,
    int N, int K)
{
    A += (long)blockIdx.z * strideA;
    C += (long)blockIdx.z * strideC;
    const int m0 = blockIdx.y * 128, n0 = blockIdx.x * 64;
    __shared__ float As[16][128];
    __shared__ float Bs[16][64];
    const int t = threadIdx.x;
    const int tx = t & 15, ty = t >> 4;
    float acc[8][4] = {};
    for (int k0 = 0; k0 < K; k0 += 16) {
        #pragma unroll
        for (int i = 0; i < 2; i++) {
            int idx = t + 256 * i;
            int row = idx >> 2;
            int kf  = (idx & 3) * 4;
            float4 av = *(const float4*)&A[(long)(m0 + row) * K + k0 + kf];
            As[kf + 0][row] = av.x; As[kf + 1][row] = av.y;
            As[kf + 2][row] = av.z; As[kf + 3][row] = av.w;
        }
        {
            int kk = t >> 4, nf = (t & 15) * 4;
            *(float4*)&Bs[kk][nf] = *(const float4*)&B[(long)(k0 + kk) * N + n0 + nf];
        }
        __syncthreads();
        #pragma unroll
        for (int kk = 0; kk < 16; kk++) {
            float a[8], bb[4];
            #pragma unroll
            for (int i = 0; i < 8; i++) a[i] = As[kk][ty * 8 + i];
            #pragma unroll
            for (int j = 0; j < 4; j++) bb[j] = Bs[kk][tx * 4 + j];
            #pragma unroll
            for (int i = 0; i < 8; i++)
                #pragma unroll
                for (int j = 0; j < 4; j++)
                    acc[i][j] += a[i] * bb[j];
        }
        __syncthreads();
    }
    #pragma unroll
    for (int i = 0; i < 8; i++) {
        float4 v = { acc[i][0], acc[i][1], acc[i][2], acc[i][3] };
        *(float4*)&C[(long)(m0 + ty * 8 + i) * N + n0 + tx * 4] = v;
    }
}

// ---------------- fp32 GEMM with bf16 output ---------------------------------
__global__ __launch_bounds__(256) void gemm_f32_bf16out(
    const float* __restrict__ A, long strideA,
    const float* __restrict__ B,
    unsigned short* __restrict__ C, long strideC,
    int N, int K)
{
    A += (long)blockIdx.z * strideA;
    C += (long)blockIdx.z * strideC;
    const int m0 = blockIdx.y * 128, n0 = blockIdx.x * 64;
    __shared__ float As[16][128];
    __shared__ float Bs[16][64];
    const int t = threadIdx.x;
    const int tx = t & 15, ty = t >> 4;
    float acc[8][4] = {};
    for (int k0 = 0; k0 < K; k0 += 16) {
        #pragma unroll
        for (int i = 0; i < 2; i++) {
            int idx = t + 256 * i;
            int row = idx >> 2;
            int kf  = (idx & 3) * 4;
            float4 av = *(const float4*)&A[(long)(m0 + row) * K + k0 + kf];
            As[kf + 0][row] = av.x; As[kf + 1][row] = av.y;
            As[kf + 2][row] = av.z; As[kf + 3][row] = av.w;
        }
        {
            int kk = t >> 4, nf = (t & 15) * 4;
            *(float4*)&Bs[kk][nf] = *(const float4*)&B[(long)(k0 + kk) * N + n0 + nf];
        }
        __syncthreads();
        #pragma unroll
        for (int kk = 0; kk < 16; kk++) {
            float a[8], bb[4];
            #pragma unroll
            for (int i = 0; i < 8; i++) a[i] = As[kk][ty * 8 + i];
            #pragma unroll
            for (int j = 0; j < 4; j++) bb[j] = Bs[kk][tx * 4 + j];
            #pragma unroll
            for (int i = 0; i < 8; i++)
                #pragma unroll
                for (int j = 0; j < 4; j++)
                    acc[i][j] += a[i] * bb[j];
        }
        __syncthreads();
    }
    #pragma unroll
    for (int i = 0; i < 8; i++) {
        ushort4 v = { f2b(acc[i][0]), f2b(acc[i][1]), f2b(acc[i][2]), f2b(acc[i][3]) };
        *(ushort4*)&C[(long)(m0 + ty * 8 + i) * N + n0 + tx * 4] = v;
    }
}

// ---------------- V transpose prep: vt[b][h][d=32][key=2048] bf16 ------------
__global__ __launch_bounds__(256) void vt_prep(
    const unsigned short* __restrict__ kvb,
    unsigned short* __restrict__ vt)
{
    const int b = blockIdx.z, h = blockIdx.y, k0 = blockIdx.x * 64;
    const int t = threadIdx.x;
    __shared__ unsigned short tile[64][48];  // rows 96B (16B-aligned)
    {
        const int key = t >> 2, dc = (t & 3) * 8;
        *(bf16x8*)&tile[key][dc] = *(const bf16x8*)(
            kvb + ((long)b * N_TOK + k0 + key) * (2 * DMODEL) + DMODEL + h * HD + dc);
    }
    __syncthreads();
    {
        const int d = t & 31, kc = (t >> 5) * 8;
        bf16x8 v;
        #pragma unroll
        for (int i = 0; i < 8; i++) v[i] = (short)tile[kc + i][d];
        *(bf16x8*)(vt + (((long)(b * NH + h)) * HD + d) * N_TOK + k0 + kc) = v;
    }
}

// ---------------- Token path: MFMA flash attention (no max needed) -----------
// grid (32,16,2), 256 thr = 4 independent waves, wave = 16 q rows.
__global__ __launch_bounds__(256) void attn_x_mfma(
    const unsigned short* __restrict__ qb,
    const unsigned short* __restrict__ kvb,
    const unsigned short* __restrict__ vt,
    float* __restrict__ ao)
{
    const int b = blockIdx.z, h = blockIdx.y;
    const int wid = threadIdx.x >> 6, lane = threadIdx.x & 63;
    const int lr = lane & 15, lg = lane >> 4;
    const int q0 = blockIdx.x * 64 + wid * 16;

    __shared__ unsigned short Pl[4][16][72];   // per-wave P tile, rows 144B
    unsigned short (*P)[72] = Pl[wid];

    const bf16x8 qfrag = *reinterpret_cast<const bf16x8*>(
        qb + ((long)b * N_ALL + q0 + lr) * DMODEL + h * HD + lg * 8);

    f32x4 o0 = {0.f,0.f,0.f,0.f}, o1 = {0.f,0.f,0.f,0.f};
    float rs0 = 0.f, rs1 = 0.f, rs2 = 0.f, rs3 = 0.f;
    const unsigned short* kbase = kvb + (long)b * N_TOK * (2 * DMODEL) + h * HD + lg * 8;
    const unsigned short* vbase = vt + ((long)(b * NH + h)) * HD * N_TOK;

    for (int k0 = 0; k0 < N_TOK; k0 += 64) {
        f32x4 s[4];
        #pragma unroll
        for (int kg = 0; kg < 4; kg++) {
            bf16x8 kf = *reinterpret_cast<const bf16x8*>(
                kbase + (long)(k0 + kg * 16 + lr) * (2 * DMODEL));
            f32x4 z = {0.f,0.f,0.f,0.f};
            s[kg] = __builtin_amdgcn_mfma_f32_16x16x32_bf16(qfrag, kf, z, 0, 0, 0);
        }
        #pragma unroll
        for (int kg = 0; kg < 4; kg++) {
            float p0 = __expf(s[kg][0] * SCALE);
            float p1 = __expf(s[kg][1] * SCALE);
            float p2 = __expf(s[kg][2] * SCALE);
            float p3 = __expf(s[kg][3] * SCALE);
            rs0 += p0; rs1 += p1; rs2 += p2; rs3 += p3;
            P[lg * 4 + 0][kg * 16 + lr] = f2b(p0);
            P[lg * 4 + 1][kg * 16 + lr] = f2b(p1);
            P[lg * 4 + 2][kg * 16 + lr] = f2b(p2);
            P[lg * 4 + 3][kg * 16 + lr] = f2b(p3);
        }
        #pragma unroll
        for (int kh = 0; kh < 2; kh++) {
            bf16x8 pf = *reinterpret_cast<const bf16x8*>(&P[lr][kh * 32 + lg * 8]);
            #pragma unroll
            for (int dg = 0; dg < 2; dg++) {
                bf16x8 vf = *reinterpret_cast<const bf16x8*>(
                    vbase + (long)(dg * 16 + lr) * N_TOK + k0 + kh * 32 + lg * 8);
                if (dg == 0) o0 = __builtin_amdgcn_mfma_f32_16x16x32_bf16(pf, vf, o0, 0, 0, 0);
                else         o1 = __builtin_amdgcn_mfma_f32_16x16x32_bf16(pf, vf, o1, 0, 0, 0);
            }
        }
    }
    float inv0, inv1, inv2, inv3;
    {
        float v;
        v = rs0; v += __shfl_xor(v,1); v += __shfl_xor(v,2); v += __shfl_xor(v,4); v += __shfl_xor(v,8); inv0 = 1.f / v;
        v = rs1; v += __shfl_xor(v,1); v += __shfl_xor(v,2); v += __shfl_xor(v,4); v += __shfl_xor(v,8); inv1 = 1.f / v;
        v = rs2; v += __shfl_xor(v,1); v += __shfl_xor(v,2); v += __shfl_xor(v,4); v += __shfl_xor(v,8); inv2 = 1.f / v;
        v = rs3; v += __shfl_xor(v,1); v += __shfl_xor(v,2); v += __shfl_xor(v,4); v += __shfl_xor(v,8); inv3 = 1.f / v;
    }
    float* aorow = ao + ((long)b * N_ALL + q0) * DMODEL + h * HD;
    aorow[(long)(lg*4+0) * DMODEL + lr]      = o0[0] * inv0;
    aorow[(long)(lg*4+1) * DMODEL + lr]      = o0[1] * inv1;
    aorow[(long)(lg*4+2) * DMODEL + lr]      = o0[2] * inv2;
    aorow[(long)(lg*4+3) * DMODEL + lr]      = o0[3] * inv3;
    aorow[(long)(lg*4+0) * DMODEL + 16 + lr] = o1[0] * inv0;
    aorow[(long)(lg*4+1) * DMODEL + 16 + lr] = o1[1] * inv1;
    aorow[(long)(lg*4+2) * DMODEL + 16 + lr] = o1[2] * inv2;
    aorow[(long)(lg*4+3) * DMODEL + 16 + lr] = o1[3] * inv3;
}

// ---------------- Cluster path: MFMA, fused colsum + PV, key-split 8 ---------
// grid (8,16,2), 256 thr = 4 waves, wave = 64 cluster rows, block = 256 keys.
__global__ __launch_bounds__(256) void attn_c_mfma(
    const unsigned short* __restrict__ qb,
    const unsigned short* __restrict__ kvb,
    const unsigned short* __restrict__ vt,
    float* __restrict__ part)    // (b,h,8,256,36)
{
    const int b = blockIdx.z, h = blockIdx.y, kblk = blockIdx.x;
    const int wid = threadIdx.x >> 6, lane = threadIdx.x & 63;
    const int lr = lane & 15, lg = lane >> 4;
    const int c0 = wid * 64;

    __shared__ unsigned short Pl[4][64][72];
    __shared__ float cs2[64][4];
    unsigned short (*P)[72] = Pl[wid];

    bf16x8 qf[4];
    #pragma unroll
    for (int qs = 0; qs < 4; qs++)
        qf[qs] = *reinterpret_cast<const bf16x8*>(
            qb + ((long)b * N_ALL + N_TOK + c0 + qs * 16 + lr) * DMODEL + h * HD + lg * 8);

    f32x4 o[4][2] = {};
    float rs[4][4] = {};
    const unsigned short* kbase = kvb + (long)b * N_TOK * (2 * DMODEL) + h * HD + lg * 8;
    const unsigned short* vbase = vt + ((long)(b * NH + h)) * HD * N_TOK;

    for (int kt = 0; kt < 4; kt++) {
        const int k0 = kblk * 256 + kt * 64;
        bf16x8 kf[4];
        #pragma unroll
        for (int kg = 0; kg < 4; kg++)
            kf[kg] = *reinterpret_cast<const bf16x8*>(
                kbase + (long)(k0 + kg * 16 + lr) * (2 * DMODEL));
        f32x4 e[4][4];
        #pragma unroll
        for (int qs = 0; qs < 4; qs++)
            #pragma unroll
            for (int kg = 0; kg < 4; kg++) {
                f32x4 z = {0.f,0.f,0.f,0.f};
                e[qs][kg] = __builtin_amdgcn_mfma_f32_16x16x32_bf16(qf[qs], kf[kg], z, 0, 0, 0);
            }
        // exp in place + per-key colsum partial over this wave's 64 clusters
        float csum[4];
        #pragma unroll
        for (int kg = 0; kg < 4; kg++) {
            float v = 0.f;
            #pragma unroll
            for (int qs = 0; qs < 4; qs++)
                #pragma unroll
                for (int r = 0; r < 4; r++) {
                    float p = __expf(e[qs][kg][r] * SCALE);
                    e[qs][kg][r] = p;
                    v += p;
                }
            v += __shfl_xor(v, 16);
            v += __shfl_xor(v, 32);
            csum[kg] = v;
        }
        // lane's own key (= lane id) partial is csum[lg]
        float own = (lg == 0) ? csum[0] : (lg == 1) ? csum[1] : (lg == 2) ? csum[2] : csum[3];
        __syncthreads();                // prior-iter cs2 reads complete
        cs2[lane][wid] = own;
        __syncthreads();
        float ics0, ics1, ics2, ics3;
        {
            f32x4 c4;
            c4 = *reinterpret_cast<const f32x4*>(&cs2[ 0 + lr][0]); ics0 = 1.f / (c4[0]+c4[1]+c4[2]+c4[3]);
            c4 = *reinterpret_cast<const f32x4*>(&cs2[16 + lr][0]); ics1 = 1.f / (c4[0]+c4[1]+c4[2]+c4[3]);
            c4 = *reinterpret_cast<const f32x4*>(&cs2[32 + lr][0]); ics2 = 1.f / (c4[0]+c4[1]+c4[2]+c4[3]);
            c4 = *reinterpret_cast<const f32x4*>(&cs2[48 + lr][0]); ics3 = 1.f / (c4[0]+c4[1]+c4[2]+c4[3]);
        }
        #pragma unroll
        for (int qs = 0; qs < 4; qs++)
            #pragma unroll
            for (int kg = 0; kg < 4; kg++) {
                const float ics = (kg == 0) ? ics0 : (kg == 1) ? ics1 : (kg == 2) ? ics2 : ics3;
                #pragma unroll
                for (int r = 0; r < 4; r++) {
                    float p = e[qs][kg][r] * ics;
                    rs[qs][r] += p;
                    P[qs * 16 + lg * 4 + r][kg * 16 + lr] = f2b(p);
                }
            }
        #pragma unroll
        for (int kh = 0; kh < 2; kh++) {
            bf16x8 pf[4];
            #pragma unroll
            for (int qs = 0; qs < 4; qs++)
                pf[qs] = *reinterpret_cast<const bf16x8*>(&P[qs * 16 + lr][kh * 32 + lg * 8]);
            #pragma unroll
            for (int dg = 0; dg < 2; dg++) {
                bf16x8 vf = *reinterpret_cast<const bf16x8*>(
                    vbase + (long)(dg * 16 + lr) * N_TOK + k0 + kh * 32 + lg * 8);
                #pragma unroll
                for (int qs = 0; qs < 4; qs++)
                    o[qs][dg] = __builtin_amdgcn_mfma_f32_16x16x32_bf16(pf[qs], vf, o[qs][dg], 0, 0, 0);
            }
        }
    }
    float* pp = part + ((((long)(b * NH + h)) * 8 + kblk) * 256) * 36;
    #pragma unroll
    for (int qs = 0; qs < 4; qs++)
        #pragma unroll
        for (int r = 0; r < 4; r++) {
            const int row = c0 + qs * 16 + lg * 4 + r;
            pp[(long)row * 36 + lr]      = o[qs][0][r];
            pp[(long)row * 36 + 16 + lr] = o[qs][1][r];
            float v = rs[qs][r];
            v += __shfl_xor(v,1); v += __shfl_xor(v,2); v += __shfl_xor(v,4); v += __shfl_xor(v,8);
            if (lr == 0) pp[(long)row * 36 + 32] = v;
        }
}

// ---------------- Cluster partial reduce -------------------------------------
__global__ __launch_bounds__(256) void attn_c_reduce(
    const float* __restrict__ part, float* __restrict__ ao)
{
    const int gid = blockIdx.x * 256 + threadIdx.x;   // 8192
    const int b = gid >> 12, h = (gid >> 8) & 15, c = gid & 255;
    float acc[32] = {};
    float rsum = 0.f;
    for (int j = 0; j < 8; j++) {
        const float* pp = part + ((((long)(b * NH + h)) * 8 + j) * 256 + c) * 36;
        #pragma unroll
        for (int e4 = 0; e4 < 8; e4++) {
            f32x4 v = *reinterpret_cast<const f32x4*>(pp + e4 * 4);
            acc[e4*4+0] += v[0]; acc[e4*4+1] += v[1];
            acc[e4*4+2] += v[2]; acc[e4*4+3] += v[3];
        }
        rsum += pp[32];
    }
    const float inv = 1.f / (rsum + 1e-5f);
    float* orow = ao + ((long)b * N_ALL + N_TOK + c) * DMODEL + h * HD;
    #pragma unroll
    for (int e = 0; e < 32; e++) orow[e] = acc[e] * inv;
}

extern "C" void kernel_launch(void* const* d_in, const int* in_sizes, int n_in,
                              void* d_out, int out_size, void* d_ws, size_t ws_size,
                              hipStream_t stream)
{
    const float* x        = (const float*)d_in[0];
    const float* clusters = (const float*)d_in[1];
    // d_in[2] token_sizes: dead input (softmax-shift-invariant)
    const float* Wq  = (const float*)d_in[3];
    const float* Wkv = (const float*)d_in[4];
    const float* Wo  = (const float*)d_in[5];
    float* out = (float*)d_out;

    char* ws = (char*)d_ws;
    unsigned short* qb  = (unsigned short*)(ws);               // 4,718,592 B
    unsigned short* kvb = (unsigned short*)(ws + 4718592);     // 8,388,608 B
    unsigned short* vt  = (unsigned short*)(ws + 13107200);    // 4,194,304 B
    float* ao   = (float*)(ws + 17301504);                     // 9,437,184 B
    float* part = (float*)(ws + 26738688);                     // 9,437,184 B

    // projections (bf16 outputs for attention)
    gemm_f32_bf16out<<<dim3(8, 16, 2), 256, 0, stream>>>(
        x, (long)N_TOK * DMODEL, Wq, qb, (long)N_ALL * DMODEL, DMODEL, DMODEL);
    gemm_f32_bf16out<<<dim3(8, 2, 2), 256, 0, stream>>>(
        clusters, (long)N_CLU * DMODEL, Wq, qb + (long)N_TOK * DMODEL, (long)N_ALL * DMODEL, DMODEL, DMODEL);
    gemm_f32_bf16out<<<dim3(16, 16, 2), 256, 0, stream>>>(
        x, (long)N_TOK * DMODEL, Wkv, kvb, (long)N_TOK * 2 * DMODEL, 2 * DMODEL, DMODEL);

    vt_prep<<<dim3(32, 16, 2), 256, 0, stream>>>(kvb, vt);

    attn_x_mfma<<<dim3(32, 16, 2), 256, 0, stream>>>(qb, kvb, vt, ao);
    attn_c_mfma<<<dim3(8, 16, 2), 256, 0, stream>>>(qb, kvb, vt, part);
    attn_c_reduce<<<dim3(32), 256, 0, stream>>>(part, ao);

    // output projections (fp32)
    gemm_f32<<<dim3(8, 16, 2), 256, 0, stream>>>(
        ao, (long)N_ALL * DMODEL, Wo, out, (long)N_TOK * DMODEL, DMODEL, DMODEL);
    gemm_f32<<<dim3(8, 2, 2), 256, 0, stream>>>(
        ao + (long)N_TOK * DMODEL, (long)N_ALL * DMODEL, Wo,
        out + (long)BATCH * N_TOK * DMODEL, (long)N_CLU * DMODEL, DMODEL, DMODEL);
}

// Round 4
// 252.300 us; speedup vs baseline: 6.2686x; 1.9310x over previous
//
#include <hip/hip_runtime.h>
#include <hip/hip_bf16.h>

#define N_TOK 2048
#define N_CLU 256
#define N_ALL 2304
#define DMODEL 512
#define NH 16
#define HD 32
#define BATCH 2
#define SCALE 0.17677669529663687f

typedef short bf16x8 __attribute__((ext_vector_type(8)));
typedef float f32x4  __attribute__((ext_vector_type(4)));
typedef unsigned short u16;

static __device__ __forceinline__ u16 f2b(float x) {
    __hip_bfloat16 h = __float2bfloat16(x);
    return *reinterpret_cast<u16*>(&h);
}
static __device__ __forceinline__ unsigned int cvt_pk_bf16(float lo, float hi) {
    unsigned int r;
    asm("v_cvt_pk_bf16_f32 %0, %1, %2" : "=v"(r) : "v"(lo), "v"(hi));
    return r;
}
static __device__ __forceinline__ void async16(u16* lds, const u16* g) {
    __builtin_amdgcn_global_load_lds(
        (const __attribute__((address_space(1))) unsigned int*)g,
        (__attribute__((address_space(3))) unsigned int*)lds, 16, 0, 0);
}

// ---------------- fp32 -> bf16 elementwise (n multiple of 2048) --------------
__global__ __launch_bounds__(256) void cvt_bf16_k(const float* __restrict__ in,
                                                  u16* __restrict__ out)
{
    const long i = ((long)blockIdx.x * 256 + threadIdx.x) * 8;
    float4 a = *(const float4*)(in + i);
    float4 b = *(const float4*)(in + i + 4);
    u16 v[8] = { f2b(a.x), f2b(a.y), f2b(a.z), f2b(a.w),
                 f2b(b.x), f2b(b.y), f2b(b.z), f2b(b.w) };
    *(bf16x8*)(out + i) = *(const bf16x8*)v;
}

// ---------------- fp32 [R][C] -> bf16 [C][R] transpose+cvt (+scale) ----------
__global__ __launch_bounds__(256) void cvtT_k(const float* __restrict__ W,
                                              u16* __restrict__ WT,
                                              int R, int C, float scale)
{
    __shared__ float tile[32][33];
    const int tx = threadIdx.x & 31, ty = threadIdx.x >> 5;
    const int c0 = blockIdx.x * 32, r0 = blockIdx.y * 32;
    #pragma unroll
    for (int i = 0; i < 4; i++)
        tile[ty + i * 8][tx] = W[(long)(r0 + ty + i * 8) * C + c0 + tx];
    __syncthreads();
    #pragma unroll
    for (int i = 0; i < 4; i++)
        WT[(long)(c0 + ty + i * 8) * R + r0 + tx] = f2b(tile[tx][ty + i * 8] * scale);
}

// ---------------- bf16 MFMA GEMM: C[M,N] = A[M,K] @ BT[N,K]^T ----------------
// 128x128 tile, BK=32, 256 thr = 4 waves (2x2 of 64x64), global_load_lds w=16.
__global__ __launch_bounds__(256) void gemm_bf16(
    const u16* __restrict__ A, long sA,
    const u16* __restrict__ BT,
    void* __restrict__ Cv, long sC,
    int N, int K, int out_fp32)
{
    const int t = threadIdx.x;
    const int m0 = blockIdx.y * 128, n0 = blockIdx.x * 128;
    A += (long)blockIdx.z * sA;
    __shared__ u16 As[128 * 32];
    __shared__ u16 Bs[128 * 32];
    const int wid = t >> 6, lane = t & 63;
    const int lr = lane & 15, lg = lane >> 4;
    const int wr = wid >> 1, wc = wid & 1;
    f32x4 acc[4][4] = {};
    const int o1 = t * 16, o2 = o1 + 4096;           // byte offsets in 8KB tile
    const int row1 = o1 >> 6, ke1 = (o1 & 63) >> 1;
    const int row2 = o2 >> 6, ke2 = (o2 & 63) >> 1;
    for (int k0 = 0; k0 < K; k0 += 32) {
        async16(As + (o1 >> 1), A  + (long)(m0 + row1) * K + k0 + ke1);
        async16(As + (o2 >> 1), A  + (long)(m0 + row2) * K + k0 + ke2);
        async16(Bs + (o1 >> 1), BT + (long)(n0 + row1) * K + k0 + ke1);
        async16(Bs + (o2 >> 1), BT + (long)(n0 + row2) * K + k0 + ke2);
        __syncthreads();
        bf16x8 af[4], bfr[4];
        #pragma unroll
        for (int i = 0; i < 4; i++) {
            af[i]  = *(const bf16x8*)&As[(wr * 64 + i * 16 + lr) * 32 + lg * 8];
            bfr[i] = *(const bf16x8*)&Bs[(wc * 64 + i * 16 + lr) * 32 + lg * 8];
        }
        #pragma unroll
        for (int mi = 0; mi < 4; mi++)
            #pragma unroll
            for (int ni = 0; ni < 4; ni++)
                acc[mi][ni] = __builtin_amdgcn_mfma_f32_16x16x32_bf16(af[mi], bfr[ni], acc[mi][ni], 0, 0, 0);
        __syncthreads();
    }
    if (out_fp32) {
        float* C = (float*)Cv + (long)blockIdx.z * sC;
        #pragma unroll
        for (int mi = 0; mi < 4; mi++)
            #pragma unroll
            for (int ni = 0; ni < 4; ni++) {
                const long rbase = m0 + wr * 64 + mi * 16 + lg * 4;
                #pragma unroll
                for (int r = 0; r < 4; r++)
                    C[(rbase + r) * N + n0 + wc * 64 + ni * 16 + lr] = acc[mi][ni][r];
            }
    } else {
        u16* C = (u16*)Cv + (long)blockIdx.z * sC;
        #pragma unroll
        for (int mi = 0; mi < 4; mi++)
            #pragma unroll
            for (int ni = 0; ni < 4; ni++) {
                const long rbase = m0 + wr * 64 + mi * 16 + lg * 4;
                #pragma unroll
                for (int r = 0; r < 4; r++)
                    C[(rbase + r) * N + n0 + wc * 64 + ni * 16 + lr] = f2b(acc[mi][ni][r]);
            }
    }
}

// ---------------- V transpose prep: vt[b][h][d=32][key=2048] bf16 ------------
__global__ __launch_bounds__(256) void vt_prep(
    const u16* __restrict__ kvb, u16* __restrict__ vt)
{
    const int b = blockIdx.z, h = blockIdx.y, k0 = blockIdx.x * 64;
    const int t = threadIdx.x;
    __shared__ u16 tile[64][48];
    {
        const int key = t >> 2, dc = (t & 3) * 8;
        *(bf16x8*)&tile[key][dc] = *(const bf16x8*)(
            kvb + ((long)b * N_TOK + k0 + key) * (2 * DMODEL) + DMODEL + h * HD + dc);
    }
    __syncthreads();
    {
        const int d = t & 31, kc = (t >> 5) * 8;
        bf16x8 v;
        #pragma unroll
        for (int i = 0; i < 8; i++) v[i] = (short)tile[kc + i][d];
        *(bf16x8*)(vt + (((long)(b * NH + h)) * HD + d) * N_TOK + k0 + kc) = v;
    }
}

// ---------------- Token path v2: swapped-QK MFMA flash, 32q/wave -------------
// grid (16,16,2), 256 thr = 4 independent waves; no block barriers.
__global__ __launch_bounds__(256) void attn_x2(
    const u16* __restrict__ qb, const u16* __restrict__ kvb,
    const u16* __restrict__ vt, u16* __restrict__ aob)
{
    const int b = blockIdx.z, h = blockIdx.y;
    const int wid = threadIdx.x >> 6, lane = threadIdx.x & 63;
    const int lr = lane & 15, lg = lane >> 4;
    const int q0 = blockIdx.x * 128 + wid * 32;

    __shared__ unsigned int Pl[4][32][36];      // per-wave P^T tile (u32 = 2 keys)
    unsigned int (*P)[36] = Pl[wid];

    bf16x8 qf[2];
    #pragma unroll
    for (int qs = 0; qs < 2; qs++)
        qf[qs] = *(const bf16x8*)(qb + ((long)b * N_ALL + q0 + qs * 16 + lr) * DMODEL + h * HD + lg * 8);

    f32x4 o[2][2] = {};
    float rs[2] = {0.f, 0.f};
    const u16* kbase = kvb + (long)b * N_TOK * (2 * DMODEL) + h * HD + lg * 8;
    const u16* vbase = vt + ((long)(b * NH + h)) * HD * N_TOK;

    for (int k0 = 0; k0 < N_TOK; k0 += 64) {
        bf16x8 kf[4];
        #pragma unroll
        for (int kg = 0; kg < 4; kg++)
            kf[kg] = *(const bf16x8*)(kbase + (long)(k0 + kg * 16 + lr) * (2 * DMODEL));
        #pragma unroll
        for (int qs = 0; qs < 2; qs++) {
            #pragma unroll
            for (int kg = 0; kg < 4; kg++) {
                f32x4 z = {0.f, 0.f, 0.f, 0.f};
                f32x4 s = __builtin_amdgcn_mfma_f32_16x16x32_bf16(kf[kg], qf[qs], z, 0, 0, 0);
                float e0 = __expf(s[0]), e1 = __expf(s[1]);
                float e2 = __expf(s[2]), e3 = __expf(s[3]);
                rs[qs] += (e0 + e1) + (e2 + e3);
                uint2 w = { cvt_pk_bf16(e0, e1), cvt_pk_bf16(e2, e3) };
                *(uint2*)&P[qs * 16 + lr][kg * 8 + lg * 2] = w;   // keys kg*16+lg*4..+3
            }
        }
        #pragma unroll
        for (int c = 0; c < 2; c++) {
            bf16x8 pb0 = *(const bf16x8*)&P[lr][c * 16 + lg * 4];       // keys 32c+8lg..+7, q=lr
            bf16x8 pb1 = *(const bf16x8*)&P[16 + lr][c * 16 + lg * 4];
            #pragma unroll
            for (int dg = 0; dg < 2; dg++) {
                bf16x8 vf = *(const bf16x8*)(vbase + (long)(dg * 16 + lr) * N_TOK + k0 + c * 32 + lg * 8);
                o[0][dg] = __builtin_amdgcn_mfma_f32_16x16x32_bf16(vf, pb0, o[0][dg], 0, 0, 0);
                o[1][dg] = __builtin_amdgcn_mfma_f32_16x16x32_bf16(vf, pb1, o[1][dg], 0, 0, 0);
            }
        }
    }
    float inv[2];
    #pragma unroll
    for (int qs = 0; qs < 2; qs++) {
        float v = rs[qs];
        v += __shfl_xor(v, 16);
        v += __shfl_xor(v, 32);
        inv[qs] = 1.f / v;
    }
    // O^T (d x q) -> LDS -> coalesced bf16 rows of ao[q][d]
    u16* Ow = (u16*)P;                              // 32 rows x 72 u16 (stride 36 u32)
    #pragma unroll
    for (int qs = 0; qs < 2; qs++)
        #pragma unroll
        for (int dg = 0; dg < 2; dg++)
            #pragma unroll
            for (int r = 0; r < 4; r++)
                Ow[(qs * 16 + lr) * 72 + dg * 16 + lg * 4 + r] = f2b(o[qs][dg][r] * inv[qs]);
    const int rrow = lane >> 2, seg = lane & 3;
    #pragma unroll
    for (int rep = 0; rep < 2; rep++) {
        bf16x8 v = *(const bf16x8*)&Ow[(rep * 16 + rrow) * 72 + seg * 8];
        *(bf16x8*)(aob + ((long)b * N_ALL + q0 + rep * 16 + rrow) * DMODEL + h * HD + seg * 8) = v;
    }
}

// ---------------- Cluster path: MFMA, fused colsum + PV, key-split 8 ---------
__global__ __launch_bounds__(256) void attn_c_mfma(
    const u16* __restrict__ qb, const u16* __restrict__ kvb,
    const u16* __restrict__ vt, float* __restrict__ part)
{
    const int b = blockIdx.z, h = blockIdx.y, kblk = blockIdx.x;
    const int wid = threadIdx.x >> 6, lane = threadIdx.x & 63;
    const int lr = lane & 15, lg = lane >> 4;
    const int c0 = wid * 64;

    __shared__ u16 Pl[4][64][72];
    __shared__ float cs2[64][4];
    u16 (*P)[72] = Pl[wid];

    bf16x8 qf[4];
    #pragma unroll
    for (int qs = 0; qs < 4; qs++)
        qf[qs] = *(const bf16x8*)(
            qb + ((long)b * N_ALL + N_TOK + c0 + qs * 16 + lr) * DMODEL + h * HD + lg * 8);

    f32x4 o[4][2] = {};
    float rs[4][4] = {};
    const u16* kbase = kvb + (long)b * N_TOK * (2 * DMODEL) + h * HD + lg * 8;
    const u16* vbase = vt + ((long)(b * NH + h)) * HD * N_TOK;

    for (int kt = 0; kt < 4; kt++) {
        const int k0 = kblk * 256 + kt * 64;
        bf16x8 kf[4];
        #pragma unroll
        for (int kg = 0; kg < 4; kg++)
            kf[kg] = *(const bf16x8*)(kbase + (long)(k0 + kg * 16 + lr) * (2 * DMODEL));
        f32x4 e[4][4];
        #pragma unroll
        for (int qs = 0; qs < 4; qs++)
            #pragma unroll
            for (int kg = 0; kg < 4; kg++) {
                f32x4 z = {0.f, 0.f, 0.f, 0.f};
                e[qs][kg] = __builtin_amdgcn_mfma_f32_16x16x32_bf16(qf[qs], kf[kg], z, 0, 0, 0);
            }
        float csum[4];
        #pragma unroll
        for (int kg = 0; kg < 4; kg++) {
            float v = 0.f;
            #pragma unroll
            for (int qs = 0; qs < 4; qs++)
                #pragma unroll
                for (int r = 0; r < 4; r++) {
                    float p = __expf(e[qs][kg][r]);      // qb pre-scaled
                    e[qs][kg][r] = p;
                    v += p;
                }
            v += __shfl_xor(v, 16);
            v += __shfl_xor(v, 32);
            csum[kg] = v;
        }
        float own = (lg == 0) ? csum[0] : (lg == 1) ? csum[1] : (lg == 2) ? csum[2] : csum[3];
        __syncthreads();
        cs2[lane][wid] = own;
        __syncthreads();
        float ics0, ics1, ics2, ics3;
        {
            f32x4 c4;
            c4 = *(const f32x4*)&cs2[ 0 + lr][0]; ics0 = 1.f / (c4[0] + c4[1] + c4[2] + c4[3]);
            c4 = *(const f32x4*)&cs2[16 + lr][0]; ics1 = 1.f / (c4[0] + c4[1] + c4[2] + c4[3]);
            c4 = *(const f32x4*)&cs2[32 + lr][0]; ics2 = 1.f / (c4[0] + c4[1] + c4[2] + c4[3]);
            c4 = *(const f32x4*)&cs2[48 + lr][0]; ics3 = 1.f / (c4[0] + c4[1] + c4[2] + c4[3]);
        }
        #pragma unroll
        for (int qs = 0; qs < 4; qs++)
            #pragma unroll
            for (int kg = 0; kg < 4; kg++) {
                const float ics = (kg == 0) ? ics0 : (kg == 1) ? ics1 : (kg == 2) ? ics2 : ics3;
                #pragma unroll
                for (int r = 0; r < 4; r++) {
                    float p = e[qs][kg][r] * ics;
                    rs[qs][r] += p;
                    P[qs * 16 + lg * 4 + r][kg * 16 + lr] = f2b(p);
                }
            }
        #pragma unroll
        for (int kh = 0; kh < 2; kh++) {
            bf16x8 pf[4];
            #pragma unroll
            for (int qs = 0; qs < 4; qs++)
                pf[qs] = *(const bf16x8*)&P[qs * 16 + lr][kh * 32 + lg * 8];
            #pragma unroll
            for (int dg = 0; dg < 2; dg++) {
                bf16x8 vf = *(const bf16x8*)(
                    vbase + (long)(dg * 16 + lr) * N_TOK + k0 + kh * 32 + lg * 8);
                #pragma unroll
                for (int qs = 0; qs < 4; qs++)
                    o[qs][dg] = __builtin_amdgcn_mfma_f32_16x16x32_bf16(pf[qs], vf, o[qs][dg], 0, 0, 0);
            }
        }
    }
    float* pp = part + ((((long)(b * NH + h)) * 8 + kblk) * 256) * 36;
    #pragma unroll
    for (int qs = 0; qs < 4; qs++)
        #pragma unroll
        for (int r = 0; r < 4; r++) {
            const int row = c0 + qs * 16 + lg * 4 + r;
            pp[(long)row * 36 + lr]      = o[qs][0][r];
            pp[(long)row * 36 + 16 + lr] = o[qs][1][r];
            float v = rs[qs][r];
            v += __shfl_xor(v, 1); v += __shfl_xor(v, 2);
            v += __shfl_xor(v, 4); v += __shfl_xor(v, 8);
            if (lr == 0) pp[(long)row * 36 + 32] = v;
        }
}

// ---------------- Cluster partial reduce (bf16 out) --------------------------
__global__ __launch_bounds__(256) void attn_c_reduce(
    const float* __restrict__ part, u16* __restrict__ aob)
{
    const int gid = blockIdx.x * 256 + threadIdx.x;   // 8192
    const int b = gid >> 12, h = (gid >> 8) & 15, c = gid & 255;
    float acc[32] = {};
    float rsum = 0.f;
    for (int j = 0; j < 8; j++) {
        const float* pp = part + ((((long)(b * NH + h)) * 8 + j) * 256 + c) * 36;
        #pragma unroll
        for (int e4 = 0; e4 < 8; e4++) {
            f32x4 v = *(const f32x4*)(pp + e4 * 4);
            acc[e4 * 4 + 0] += v[0]; acc[e4 * 4 + 1] += v[1];
            acc[e4 * 4 + 2] += v[2]; acc[e4 * 4 + 3] += v[3];
        }
        rsum += pp[32];
    }
    const float inv = 1.f / (rsum + 1e-5f);
    u16* orow = aob + ((long)b * N_ALL + N_TOK + c) * DMODEL + h * HD;
    #pragma unroll
    for (int e = 0; e < 32; e++) orow[e] = f2b(acc[e] * inv);
}

extern "C" void kernel_launch(void* const* d_in, const int* in_sizes, int n_in,
                              void* d_out, int out_size, void* d_ws, size_t ws_size,
                              hipStream_t stream)
{
    const float* x        = (const float*)d_in[0];
    const float* clusters = (const float*)d_in[1];
    // d_in[2] token_sizes: dead input (softmax-shift-invariant)
    const float* Wq  = (const float*)d_in[3];
    const float* Wkv = (const float*)d_in[4];
    const float* Wo  = (const float*)d_in[5];
    float* out = (float*)d_out;

    char* ws = (char*)d_ws;
    u16*   xb   = (u16*)(ws);                     //  4,194,304
    u16*   cb   = (u16*)(ws + 4194304);           //    524,288
    u16*   WqT  = (u16*)(ws + 4718592);           //    524,288
    u16*   WkvT = (u16*)(ws + 5242880);           //  1,048,576
    u16*   WoT  = (u16*)(ws + 6291456);           //    524,288
    u16*   qb   = (u16*)(ws + 6815744);           //  4,718,592
    u16*   kvb  = (u16*)(ws + 11534336);          //  8,388,608
    u16*   vt   = (u16*)(ws + 19922944);          //  4,194,304
    u16*   aob  = (u16*)(ws + 24117248);          //  4,718,592
    float* part = (float*)(ws + 28835840);        //  9,437,184  (end 38,273,024)

    // input conversions
    cvt_bf16_k<<<dim3(1024), 256, 0, stream>>>(x, xb);
    cvt_bf16_k<<<dim3(128),  256, 0, stream>>>(clusters, cb);
    cvtT_k<<<dim3(16, 16), 256, 0, stream>>>(Wq,  WqT,  512,  512, SCALE); // fold 1/sqrt(hd)
    cvtT_k<<<dim3(32, 16), 256, 0, stream>>>(Wkv, WkvT, 512, 1024, 1.f);
    cvtT_k<<<dim3(16, 16), 256, 0, stream>>>(Wo,  WoT,  512,  512, 1.f);

    // projections (bf16 MFMA)
    gemm_bf16<<<dim3(4, 16, 2), 256, 0, stream>>>(
        xb, (long)N_TOK * DMODEL, WqT, qb, (long)N_ALL * DMODEL, DMODEL, DMODEL, 0);
    gemm_bf16<<<dim3(4, 2, 2), 256, 0, stream>>>(
        cb, (long)N_CLU * DMODEL, WqT, qb + (long)N_TOK * DMODEL, (long)N_ALL * DMODEL, DMODEL, DMODEL, 0);
    gemm_bf16<<<dim3(8, 16, 2), 256, 0, stream>>>(
        xb, (long)N_TOK * DMODEL, WkvT, kvb, (long)N_TOK * 2 * DMODEL, 2 * DMODEL, DMODEL, 0);

    vt_prep<<<dim3(32, 16, 2), 256, 0, stream>>>(kvb, vt);

    attn_x2<<<dim3(16, 16, 2), 256, 0, stream>>>(qb, kvb, vt, aob);
    attn_c_mfma<<<dim3(8, 16, 2), 256, 0, stream>>>(qb, kvb, vt, part);
    attn_c_reduce<<<dim3(32), 256, 0, stream>>>(part, aob);

    // output projections (bf16 MFMA, fp32 out)
    gemm_bf16<<<dim3(4, 16, 2), 256, 0, stream>>>(
        aob, (long)N_ALL * DMODEL, WoT, out, (long)N_TOK * DMODEL, DMODEL, DMODEL, 1);
    gemm_bf16<<<dim3(4, 2, 2), 256, 0, stream>>>(
        aob + (long)N_TOK * DMODEL, (long)N_ALL * DMODEL, WoT,
        out + (long)BATCH * N_TOK * DMODEL, (long)N_CLU * DMODEL, DMODEL, DMODEL, 1);
}

// Round 8
// 221.515 us; speedup vs baseline: 7.1398x; 1.1390x over previous
//
#include <hip/hip_runtime.h>
#include <hip/hip_bf16.h>

#define N_TOK 2048
#define N_CLU 256
#define N_ALL 2304
#define DMODEL 512
#define NH 16
#define HD 32
#define BATCH 2
// (1/sqrt(32)) * log2(e): folded into WqT so attention uses raw exp2
#define EXPSCALE 0.25503486f

typedef short bf16x8 __attribute__((ext_vector_type(8)));
typedef float f32x4  __attribute__((ext_vector_type(4)));
typedef unsigned short u16;

static __device__ __forceinline__ u16 f2b(float x) {
    __hip_bfloat16 h = __float2bfloat16(x);
    return *reinterpret_cast<u16*>(&h);
}
static __device__ __forceinline__ unsigned int cvt_pk_bf16(float lo, float hi) {
    unsigned int r;
    asm("v_cvt_pk_bf16_f32 %0, %1, %2" : "=v"(r) : "v"(lo), "v"(hi));
    return r;
}
#if __has_builtin(__builtin_amdgcn_exp2f)
#define EXP2(x) __builtin_amdgcn_exp2f(x)
#else
#define EXP2(x) exp2f(x)
#endif
static __device__ __forceinline__ void async16(u16* lds, const u16* g) {
    __builtin_amdgcn_global_load_lds(
        (const __attribute__((address_space(1))) unsigned int*)g,
        (__attribute__((address_space(3))) unsigned int*)lds, 16, 0, 0);
}

// ---------------- fp32 -> bf16 elementwise (n multiple of 2048) --------------
__global__ __launch_bounds__(256) void cvt_bf16_k(const float* __restrict__ in,
                                                  u16* __restrict__ out)
{
    const long i = ((long)blockIdx.x * 256 + threadIdx.x) * 8;
    float4 a = *(const float4*)(in + i);
    float4 b = *(const float4*)(in + i + 4);
    u16 v[8] = { f2b(a.x), f2b(a.y), f2b(a.z), f2b(a.w),
                 f2b(b.x), f2b(b.y), f2b(b.z), f2b(b.w) };
    *(bf16x8*)(out + i) = *(const bf16x8*)v;
}

// ---------------- fp32 [R][C] -> bf16 [C][R] transpose+cvt (+scale) ----------
__global__ __launch_bounds__(256) void cvtT_k(const float* __restrict__ W,
                                              u16* __restrict__ WT,
                                              int R, int C, float scale)
{
    __shared__ float tile[32][33];
    const int tx = threadIdx.x & 31, ty = threadIdx.x >> 5;
    const int c0 = blockIdx.x * 32, r0 = blockIdx.y * 32;
    #pragma unroll
    for (int i = 0; i < 4; i++)
        tile[ty + i * 8][tx] = W[(long)(r0 + ty + i * 8) * C + c0 + tx];
    __syncthreads();
    #pragma unroll
    for (int i = 0; i < 4; i++)
        WT[(long)(c0 + ty + i * 8) * R + r0 + tx] = f2b(tile[tx][ty + i * 8] * scale);
}

// ---------------- bf16 MFMA GEMM: C[M,N] = A[M,K] @ BT[N,K]^T ----------------
// 128x128 tile, BK=32, 256 thr. mode 0: bf16 out; mode 1: fp32 out with
// aob-row -> output-row remap (tokens then clusters, batch-major blocks).
__global__ __launch_bounds__(256) void gemm_bf16(
    const u16* __restrict__ A, long sA,
    const u16* __restrict__ BT,
    void* __restrict__ Cv, long sC,
    int N, int K, int mode)
{
    const int t = threadIdx.x;
    const int m0 = blockIdx.y * 128, n0 = blockIdx.x * 128;
    A += (long)blockIdx.z * sA;
    __shared__ u16 As[128 * 32];
    __shared__ u16 Bs[128 * 32];
    const int wid = t >> 6, lane = t & 63;
    const int lr = lane & 15, lg = lane >> 4;
    const int wr = wid >> 1, wc = wid & 1;
    f32x4 acc[4][4] = {};
    const int o1 = t * 16, o2 = o1 + 4096;
    const int row1 = o1 >> 6, ke1 = (o1 & 63) >> 1;
    const int row2 = o2 >> 6, ke2 = (o2 & 63) >> 1;
    for (int k0 = 0; k0 < K; k0 += 32) {
        async16(As + (o1 >> 1), A  + (long)(m0 + row1) * K + k0 + ke1);
        async16(As + (o2 >> 1), A  + (long)(m0 + row2) * K + k0 + ke2);
        async16(Bs + (o1 >> 1), BT + (long)(n0 + row1) * K + k0 + ke1);
        async16(Bs + (o2 >> 1), BT + (long)(n0 + row2) * K + k0 + ke2);
        __syncthreads();
        bf16x8 af[4], bfr[4];
        #pragma unroll
        for (int i = 0; i < 4; i++) {
            af[i]  = *(const bf16x8*)&As[(wr * 64 + i * 16 + lr) * 32 + lg * 8];
            bfr[i] = *(const bf16x8*)&Bs[(wc * 64 + i * 16 + lr) * 32 + lg * 8];
        }
        #pragma unroll
        for (int mi = 0; mi < 4; mi++)
            #pragma unroll
            for (int ni = 0; ni < 4; ni++)
                acc[mi][ni] = __builtin_amdgcn_mfma_f32_16x16x32_bf16(af[mi], bfr[ni], acc[mi][ni], 0, 0, 0);
        __syncthreads();
    }
    if (mode == 1) {
        float* C = (float*)Cv;
        #pragma unroll
        for (int mi = 0; mi < 4; mi++)
            #pragma unroll
            for (int ni = 0; ni < 4; ni++) {
                const int rbase = m0 + wr * 64 + mi * 16 + lg * 4;
                #pragma unroll
                for (int r = 0; r < 4; r++) {
                    int rw = rbase + r;                 // 0..4607 (aob row)
                    int bb = rw >= N_ALL;
                    int w  = rw - bb * N_ALL;
                    long orow = (w < N_TOK) ? ((long)bb * N_TOK + w)
                                            : (2L * N_TOK + (long)bb * N_CLU + (w - N_TOK));
                    C[orow * N + n0 + wc * 64 + ni * 16 + lr] = acc[mi][ni][r];
                }
            }
    } else {
        u16* C = (u16*)Cv + (long)blockIdx.z * sC;
        #pragma unroll
        for (int mi = 0; mi < 4; mi++)
            #pragma unroll
            for (int ni = 0; ni < 4; ni++) {
                const long rbase = m0 + wr * 64 + mi * 16 + lg * 4;
                #pragma unroll
                for (int r = 0; r < 4; r++)
                    C[(rbase + r) * N + n0 + wc * 64 + ni * 16 + lr] = f2b(acc[mi][ni][r]);
            }
    }
}

// ---------------- V transpose prep: vt[b][h][d=32][key=2048] bf16 ------------
__global__ __launch_bounds__(256) void vt_prep(
    const u16* __restrict__ qkv, u16* __restrict__ vt)
{
    const int b = blockIdx.z, h = blockIdx.y, k0 = blockIdx.x * 64;
    const int t = threadIdx.x;
    __shared__ u16 tile[64][48];
    {
        const int key = t >> 2, dc = (t & 3) * 8;
        *(bf16x8*)&tile[key][dc] = *(const bf16x8*)(
            qkv + ((long)b * N_TOK + k0 + key) * 1536 + 1024 + h * HD + dc);
    }
    __syncthreads();
    {
        const int d = t & 31, kc = (t >> 5) * 8;
        bf16x8 v;
        #pragma unroll
        for (int i = 0; i < 8; i++) v[i] = (short)tile[kc + i][d];
        *(bf16x8*)(vt + (((long)(b * NH + h)) * HD + d) * N_TOK + k0 + kc) = v;
    }
}

// ---------------- Token path v3: 8 waves, in-block key-split -----------------
// grid (16,16,2), 512 thr. Waves 0-3: q-subtiles x keys [0,1024);
// waves 4-7: same q-subtiles x keys [1024,2048). Unnormalized partials
// combine exactly (no max subtraction anywhere).
__global__ __launch_bounds__(512) void attn_x3(
    const u16* __restrict__ qkv, const u16* __restrict__ vt,
    u16* __restrict__ aob)
{
    const int b = blockIdx.z, h = blockIdx.y;
    const int wid = threadIdx.x >> 6, lane = threadIdx.x & 63;
    const int lr = lane & 15, lg = lane >> 4;
    const int q0 = blockIdx.x * 128 + (wid & 3) * 32;
    const int khalf = wid >> 2;

    __shared__ unsigned int P[8][32][32];   // per-wave P^T tile, XOR-swizzled
    __shared__ float comb[4][64][18];       // key-half combine
    __shared__ u16 Ot[4][32][40];           // per-wave O transpose

    unsigned int (*Pw)[32] = P[wid];
    const int sw = 4 * (lr & 7);            // swizzle: col ^= 4*(qrow&7)

    bf16x8 qf[2];
    #pragma unroll
    for (int qs = 0; qs < 2; qs++)
        qf[qs] = *(const bf16x8*)(
            qkv + ((long)b * N_TOK + q0 + qs * 16 + lr) * 1536 + h * HD + lg * 8);

    f32x4 o[2][2] = {};
    float rs[2] = {0.f, 0.f};
    const u16* kbase = qkv + (long)b * N_TOK * 1536 + 512 + h * HD + lg * 8;
    const u16* vbase = vt + ((long)(b * NH + h)) * HD * N_TOK;

    const int kend = khalf * 1024 + 1024;
    for (int k0 = khalf * 1024; k0 < kend; k0 += 64) {
        bf16x8 kf[4];
        #pragma unroll
        for (int kg = 0; kg < 4; kg++)
            kf[kg] = *(const bf16x8*)(kbase + (long)(k0 + kg * 16 + lr) * 1536);
        #pragma unroll
        for (int qs = 0; qs < 2; qs++) {
            #pragma unroll
            for (int kg = 0; kg < 4; kg++) {
                f32x4 z = {0.f, 0.f, 0.f, 0.f};
                f32x4 s = __builtin_amdgcn_mfma_f32_16x16x32_bf16(kf[kg], qf[qs], z, 0, 0, 0);
                float e0 = EXP2(s[0]), e1 = EXP2(s[1]);
                float e2 = EXP2(s[2]), e3 = EXP2(s[3]);
                rs[qs] += (e0 + e1) + (e2 + e3);
                uint2 w = { cvt_pk_bf16(e0, e1), cvt_pk_bf16(e2, e3) };
                *(uint2*)&Pw[qs * 16 + lr][(kg * 8 + lg * 2) ^ sw] = w;
            }
        }
        #pragma unroll
        for (int c = 0; c < 2; c++) {
            bf16x8 pb0 = *(const bf16x8*)&Pw[lr][(c * 16 + lg * 4) ^ sw];
            bf16x8 pb1 = *(const bf16x8*)&Pw[16 + lr][(c * 16 + lg * 4) ^ sw];
            #pragma unroll
            for (int dg = 0; dg < 2; dg++) {
                bf16x8 vf = *(const bf16x8*)(
                    vbase + (long)(dg * 16 + lr) * N_TOK + k0 + c * 32 + lg * 8);
                o[0][dg] = __builtin_amdgcn_mfma_f32_16x16x32_bf16(vf, pb0, o[0][dg], 0, 0, 0);
                o[1][dg] = __builtin_amdgcn_mfma_f32_16x16x32_bf16(vf, pb1, o[1][dg], 0, 0, 0);
            }
        }
    }
    #pragma unroll
    for (int qs = 0; qs < 2; qs++) {
        rs[qs] += __shfl_xor(rs[qs], 16);
        rs[qs] += __shfl_xor(rs[qs], 32);
    }
    if (wid >= 4) {
        float* cp = &comb[wid - 4][lane][0];
        #pragma unroll
        for (int qs = 0; qs < 2; qs++)
            #pragma unroll
            for (int dg = 0; dg < 2; dg++)
                #pragma unroll
                for (int r = 0; r < 4; r++)
                    cp[qs * 8 + dg * 4 + r] = o[qs][dg][r];
        cp[16] = rs[0];
        cp[17] = rs[1];
    }
    __syncthreads();
    if (wid < 4) {
        const float* cp = &comb[wid][lane][0];
        #pragma unroll
        for (int qs = 0; qs < 2; qs++)
            #pragma unroll
            for (int dg = 0; dg < 2; dg++)
                #pragma unroll
                for (int r = 0; r < 4; r++)
                    o[qs][dg][r] += cp[qs * 8 + dg * 4 + r];
        rs[0] += cp[16];
        rs[1] += cp[17];
        const float inv0 = 1.f / rs[0], inv1 = 1.f / rs[1];
        #pragma unroll
        for (int dg = 0; dg < 2; dg++)
            #pragma unroll
            for (int r = 0; r < 4; r++) {
                Ot[wid][lr][dg * 16 + lg * 4 + r]      = f2b(o[0][dg][r] * inv0);
                Ot[wid][16 + lr][dg * 16 + lg * 4 + r] = f2b(o[1][dg][r] * inv1);
            }
        const int rrow = lane >> 2, seg = lane & 3;
        #pragma unroll
        for (int rep = 0; rep < 2; rep++) {
            bf16x8 v = *(const bf16x8*)&Ot[wid][rep * 16 + rrow][seg * 8];
            *(bf16x8*)(aob + ((long)b * N_ALL + q0 + rep * 16 + rrow) * DMODEL + h * HD + seg * 8) = v;
        }
    }
}

// ---------------- Cluster path: MFMA, fused colsum + PV, key-split 8 ---------
__global__ __launch_bounds__(256) void attn_c_mfma(
    const u16* __restrict__ qc, const u16* __restrict__ qkv,
    const u16* __restrict__ vt, float* __restrict__ part)
{
    const int b = blockIdx.z, h = blockIdx.y, kblk = blockIdx.x;
    const int wid = threadIdx.x >> 6, lane = threadIdx.x & 63;
    const int lr = lane & 15, lg = lane >> 4;
    const int c0 = wid * 64;

    __shared__ u16 Pl[4][64][72];
    __shared__ float cs2[64][4];
    u16 (*P)[72] = Pl[wid];

    bf16x8 qf[4];
    #pragma unroll
    for (int qs = 0; qs < 4; qs++)
        qf[qs] = *(const bf16x8*)(
            qc + ((long)(b * N_CLU) + c0 + qs * 16 + lr) * DMODEL + h * HD + lg * 8);

    f32x4 o[4][2] = {};
    float rs[4][4] = {};
    const u16* kbase = qkv + (long)b * N_TOK * 1536 + 512 + h * HD + lg * 8;
    const u16* vbase = vt + ((long)(b * NH + h)) * HD * N_TOK;

    for (int kt = 0; kt < 4; kt++) {
        const int k0 = kblk * 256 + kt * 64;
        bf16x8 kf[4];
        #pragma unroll
        for (int kg = 0; kg < 4; kg++)
            kf[kg] = *(const bf16x8*)(kbase + (long)(k0 + kg * 16 + lr) * 1536);
        f32x4 e[4][4];
        #pragma unroll
        for (int qs = 0; qs < 4; qs++)
            #pragma unroll
            for (int kg = 0; kg < 4; kg++) {
                f32x4 z = {0.f, 0.f, 0.f, 0.f};
                e[qs][kg] = __builtin_amdgcn_mfma_f32_16x16x32_bf16(qf[qs], kf[kg], z, 0, 0, 0);
            }
        float csum[4];
        #pragma unroll
        for (int kg = 0; kg < 4; kg++) {
            float v = 0.f;
            #pragma unroll
            for (int qs = 0; qs < 4; qs++)
                #pragma unroll
                for (int r = 0; r < 4; r++) {
                    float p = EXP2(e[qs][kg][r]);     // qc pre-scaled by log2e
                    e[qs][kg][r] = p;
                    v += p;
                }
            v += __shfl_xor(v, 16);
            v += __shfl_xor(v, 32);
            csum[kg] = v;
        }
        float own = (lg == 0) ? csum[0] : (lg == 1) ? csum[1] : (lg == 2) ? csum[2] : csum[3];
        __syncthreads();
        cs2[lane][wid] = own;
        __syncthreads();
        float ics0, ics1, ics2, ics3;
        {
            f32x4 c4;
            c4 = *(const f32x4*)&cs2[ 0 + lr][0]; ics0 = 1.f / (c4[0] + c4[1] + c4[2] + c4[3]);
            c4 = *(const f32x4*)&cs2[16 + lr][0]; ics1 = 1.f / (c4[0] + c4[1] + c4[2] + c4[3]);
            c4 = *(const f32x4*)&cs2[32 + lr][0]; ics2 = 1.f / (c4[0] + c4[1] + c4[2] + c4[3]);
            c4 = *(const f32x4*)&cs2[48 + lr][0]; ics3 = 1.f / (c4[0] + c4[1] + c4[2] + c4[3]);
        }
        #pragma unroll
        for (int qs = 0; qs < 4; qs++)
            #pragma unroll
            for (int kg = 0; kg < 4; kg++) {
                const float ics = (kg == 0) ? ics0 : (kg == 1) ? ics1 : (kg == 2) ? ics2 : ics3;
                #pragma unroll
                for (int r = 0; r < 4; r++) {
                    float p = e[qs][kg][r] * ics;
                    rs[qs][r] += p;
                    P[qs * 16 + lg * 4 + r][kg * 16 + lr] = f2b(p);
                }
            }
        #pragma unroll
        for (int kh = 0; kh < 2; kh++) {
            bf16x8 pf[4];
            #pragma unroll
            for (int qs = 0; qs < 4; qs++)
                pf[qs] = *(const bf16x8*)&P[qs * 16 + lr][kh * 32 + lg * 8];
            #pragma unroll
            for (int dg = 0; dg < 2; dg++) {
                bf16x8 vf = *(const bf16x8*)(
                    vbase + (long)(dg * 16 + lr) * N_TOK + k0 + kh * 32 + lg * 8);
                #pragma unroll
                for (int qs = 0; qs < 4; qs++)
                    o[qs][dg] = __builtin_amdgcn_mfma_f32_16x16x32_bf16(pf[qs], vf, o[qs][dg], 0, 0, 0);
            }
        }
    }
    float* pp = part + ((((long)(b * NH + h)) * 8 + kblk) * 256) * 36;
    #pragma unroll
    for (int qs = 0; qs < 4; qs++)
        #pragma unroll
        for (int r = 0; r < 4; r++) {
            const int row = c0 + qs * 16 + lg * 4 + r;
            pp[(long)row * 36 + lr]      = o[qs][0][r];
            pp[(long)row * 36 + 16 + lr] = o[qs][1][r];
            float v = rs[qs][r];
            v += __shfl_xor(v, 1); v += __shfl_xor(v, 2);
            v += __shfl_xor(v, 4); v += __shfl_xor(v, 8);
            if (lr == 0) pp[(long)row * 36 + 32] = v;
        }
}

// ---------------- Cluster partial reduce (bf16 out) --------------------------
__global__ __launch_bounds__(256) void attn_c_reduce(
    const float* __restrict__ part, u16* __restrict__ aob)
{
    const int gid = blockIdx.x * 256 + threadIdx.x;   // 8192
    const int b = gid >> 12, h = (gid >> 8) & 15, c = gid & 255;
    float acc[32] = {};
    float rsum = 0.f;
    for (int j = 0; j < 8; j++) {
        const float* pp = part + ((((long)(b * NH + h)) * 8 + j) * 256 + c) * 36;
        #pragma unroll
        for (int e4 = 0; e4 < 8; e4++) {
            f32x4 v = *(const f32x4*)(pp + e4 * 4);
            acc[e4 * 4 + 0] += v[0]; acc[e4 * 4 + 1] += v[1];
            acc[e4 * 4 + 2] += v[2]; acc[e4 * 4 + 3] += v[3];
        }
        rsum += pp[32];
    }
    const float inv = 1.f / (rsum + 1e-5f);
    u16* orow = aob + ((long)b * N_ALL + N_TOK + c) * DMODEL + h * HD;
    #pragma unroll
    for (int e = 0; e < 32; e++) orow[e] = f2b(acc[e] * inv);
}

extern "C" void kernel_launch(void* const* d_in, const int* in_sizes, int n_in,
                              void* d_out, int out_size, void* d_ws, size_t ws_size,
                              hipStream_t stream)
{
    const float* x        = (const float*)d_in[0];
    const float* clusters = (const float*)d_in[1];
    // d_in[2] token_sizes: dead input (softmax-shift-invariant)
    const float* Wq  = (const float*)d_in[3];
    const float* Wkv = (const float*)d_in[4];
    const float* Wo  = (const float*)d_in[5];
    float* out = (float*)d_out;

    char* ws = (char*)d_ws;
    u16*   xb    = (u16*)(ws);                    //  4,194,304
    u16*   cb    = (u16*)(ws + 4194304);          //    524,288
    u16*   WcatT = (u16*)(ws + 4718592);          //  1,572,864  [1536][512]
    u16*   WoT   = (u16*)(ws + 6291456);          //    524,288
    u16*   qkv   = (u16*)(ws + 6815744);          // 12,582,912  [2][2048][1536]
    u16*   qc    = (u16*)(ws + 19398656);         //    524,288  [2][256][512]
    u16*   vt    = (u16*)(ws + 19922944);         //  4,194,304
    u16*   aob   = (u16*)(ws + 24117248);         //  4,718,592
    float* part  = (float*)(ws + 28835840);       //  9,437,184  (end 38,273,024)

    // input conversions (log2e*scale folded into Wq)
    cvt_bf16_k<<<dim3(1024), 256, 0, stream>>>(x, xb);
    cvt_bf16_k<<<dim3(128),  256, 0, stream>>>(clusters, cb);
    cvtT_k<<<dim3(16, 16), 256, 0, stream>>>(Wq,  WcatT,             512,  512, EXPSCALE);
    cvtT_k<<<dim3(32, 16), 256, 0, stream>>>(Wkv, WcatT + 512 * 512, 512, 1024, 1.f);
    cvtT_k<<<dim3(16, 16), 256, 0, stream>>>(Wo,  WoT,               512,  512, 1.f);

    // fused q|k|v projection: qkv = x @ [Wq*s | Wkv]   (N = 1536)
    gemm_bf16<<<dim3(12, 16, 2), 256, 0, stream>>>(
        xb, (long)N_TOK * DMODEL, WcatT, qkv, (long)N_TOK * 1536, 1536, DMODEL, 0);
    // cluster q projection (N = 512)
    gemm_bf16<<<dim3(4, 2, 2), 256, 0, stream>>>(
        cb, (long)N_CLU * DMODEL, WcatT, qc, (long)N_CLU * DMODEL, DMODEL, DMODEL, 0);

    vt_prep<<<dim3(32, 16, 2), 256, 0, stream>>>(qkv, vt);

    attn_x3<<<dim3(16, 16, 2), 512, 0, stream>>>(qkv, vt, aob);
    attn_c_mfma<<<dim3(8, 16, 2), 256, 0, stream>>>(qc, qkv, vt, part);
    attn_c_reduce<<<dim3(32), 256, 0, stream>>>(part, aob);

    // merged output projection: [aob 4608x512] @ Wo -> out (row-remapped)
    gemm_bf16<<<dim3(4, 36, 1), 256, 0, stream>>>(
        aob, 0, WoT, out, 0, DMODEL, DMODEL, 1);
}

// Round 14
// 221.023 us; speedup vs baseline: 7.1557x; 1.0022x over previous
//
#include <hip/hip_runtime.h>
#include <hip/hip_bf16.h>

#define N_TOK 2048
#define N_CLU 256
#define N_ALL 2304
#define DMODEL 512
#define NH 16
#define HD 32
#define BATCH 2
// (1/sqrt(32)) * log2(e): folded into WqT so attention uses raw exp2
#define EXPSCALE 0.25503486f

typedef short bf16x8 __attribute__((ext_vector_type(8)));
typedef float f32x4  __attribute__((ext_vector_type(4)));
typedef unsigned short u16;

static __device__ __forceinline__ u16 f2b(float x) {
    __hip_bfloat16 h = __float2bfloat16(x);
    return *reinterpret_cast<u16*>(&h);
}
static __device__ __forceinline__ unsigned int cvt_pk_bf16(float lo, float hi) {
    unsigned int r;
    asm("v_cvt_pk_bf16_f32 %0, %1, %2" : "=v"(r) : "v"(lo), "v"(hi));
    return r;
}
#if __has_builtin(__builtin_amdgcn_exp2f)
#define EXP2(x) __builtin_amdgcn_exp2f(x)
#else
#define EXP2(x) exp2f(x)
#endif
static __device__ __forceinline__ void async16(u16* lds, const u16* g) {
    __builtin_amdgcn_global_load_lds(
        (const __attribute__((address_space(1))) unsigned int*)g,
        (__attribute__((address_space(3))) unsigned int*)lds, 16, 0, 0);
}

// ---------------- fp32 -> bf16 elementwise (n multiple of 2048) --------------
__global__ __launch_bounds__(256) void cvt_bf16_k(const float* __restrict__ in,
                                                  u16* __restrict__ out)
{
    const long i = ((long)blockIdx.x * 256 + threadIdx.x) * 8;
    float4 a = *(const float4*)(in + i);
    float4 b = *(const float4*)(in + i + 4);
    u16 v[8] = { f2b(a.x), f2b(a.y), f2b(a.z), f2b(a.w),
                 f2b(b.x), f2b(b.y), f2b(b.z), f2b(b.w) };
    *(bf16x8*)(out + i) = *(const bf16x8*)v;
}

// ---------------- fp32 [R][C] -> bf16 [C][R] transpose+cvt (+scale) ----------
__global__ __launch_bounds__(256) void cvtT_k(const float* __restrict__ W,
                                              u16* __restrict__ WT,
                                              int R, int C, float scale)
{
    __shared__ float tile[32][33];
    const int tx = threadIdx.x & 31, ty = threadIdx.x >> 5;
    const int c0 = blockIdx.x * 32, r0 = blockIdx.y * 32;
    #pragma unroll
    for (int i = 0; i < 4; i++)
        tile[ty + i * 8][tx] = W[(long)(r0 + ty + i * 8) * C + c0 + tx];
    __syncthreads();
    #pragma unroll
    for (int i = 0; i < 4; i++)
        WT[(long)(c0 + ty + i * 8) * R + r0 + tx] = f2b(tile[tx][ty + i * 8] * scale);
}

// ---------------- bf16 MFMA GEMM: C[M,N] = A[M,K] @ BT[N,K]^T ----------------
// 128x128 tile, BK=32, 256 thr. mode 0: bf16 out; mode 1: fp32 out with
// aob-row -> output-row remap (tokens then clusters, batch-major blocks).
__global__ __launch_bounds__(256) void gemm_bf16(
    const u16* __restrict__ A, long sA,
    const u16* __restrict__ BT,
    void* __restrict__ Cv, long sC,
    int N, int K, int mode)
{
    const int t = threadIdx.x;
    const int m0 = blockIdx.y * 128, n0 = blockIdx.x * 128;
    A += (long)blockIdx.z * sA;
    __shared__ u16 As[128 * 32];
    __shared__ u16 Bs[128 * 32];
    const int wid = t >> 6, lane = t & 63;
    const int lr = lane & 15, lg = lane >> 4;
    const int wr = wid >> 1, wc = wid & 1;
    f32x4 acc[4][4] = {};
    const int o1 = t * 16, o2 = o1 + 4096;
    const int row1 = o1 >> 6, ke1 = (o1 & 63) >> 1;
    const int row2 = o2 >> 6, ke2 = (o2 & 63) >> 1;
    for (int k0 = 0; k0 < K; k0 += 32) {
        async16(As + (o1 >> 1), A  + (long)(m0 + row1) * K + k0 + ke1);
        async16(As + (o2 >> 1), A  + (long)(m0 + row2) * K + k0 + ke2);
        async16(Bs + (o1 >> 1), BT + (long)(n0 + row1) * K + k0 + ke1);
        async16(Bs + (o2 >> 1), BT + (long)(n0 + row2) * K + k0 + ke2);
        __syncthreads();
        bf16x8 af[4], bfr[4];
        #pragma unroll
        for (int i = 0; i < 4; i++) {
            af[i]  = *(const bf16x8*)&As[(wr * 64 + i * 16 + lr) * 32 + lg * 8];
            bfr[i] = *(const bf16x8*)&Bs[(wc * 64 + i * 16 + lr) * 32 + lg * 8];
        }
        #pragma unroll
        for (int mi = 0; mi < 4; mi++)
            #pragma unroll
            for (int ni = 0; ni < 4; ni++)
                acc[mi][ni] = __builtin_amdgcn_mfma_f32_16x16x32_bf16(af[mi], bfr[ni], acc[mi][ni], 0, 0, 0);
        __syncthreads();
    }
    if (mode == 1) {
        float* C = (float*)Cv;
        #pragma unroll
        for (int mi = 0; mi < 4; mi++)
            #pragma unroll
            for (int ni = 0; ni < 4; ni++) {
                const int rbase = m0 + wr * 64 + mi * 16 + lg * 4;
                #pragma unroll
                for (int r = 0; r < 4; r++) {
                    int rw = rbase + r;                 // 0..4607 (aob row)
                    int bb = rw >= N_ALL;
                    int w  = rw - bb * N_ALL;
                    long orow = (w < N_TOK) ? ((long)bb * N_TOK + w)
                                            : (2L * N_TOK + (long)bb * N_CLU + (w - N_TOK));
                    C[orow * N + n0 + wc * 64 + ni * 16 + lr] = acc[mi][ni][r];
                }
            }
    } else {
        u16* C = (u16*)Cv + (long)blockIdx.z * sC;
        #pragma unroll
        for (int mi = 0; mi < 4; mi++)
            #pragma unroll
            for (int ni = 0; ni < 4; ni++) {
                const long rbase = m0 + wr * 64 + mi * 16 + lg * 4;
                #pragma unroll
                for (int r = 0; r < 4; r++)
                    C[(rbase + r) * N + n0 + wc * 64 + ni * 16 + lr] = f2b(acc[mi][ni][r]);
            }
    }
}

// ---------------- V transpose prep: vt[b][h][d=32][key=2048] bf16 ------------
__global__ __launch_bounds__(256) void vt_prep(
    const u16* __restrict__ qkv, u16* __restrict__ vt)
{
    const int b = blockIdx.z, h = blockIdx.y, k0 = blockIdx.x * 64;
    const int t = threadIdx.x;
    __shared__ u16 tile[64][48];
    {
        const int key = t >> 2, dc = (t & 3) * 8;
        *(bf16x8*)&tile[key][dc] = *(const bf16x8*)(
            qkv + ((long)b * N_TOK + k0 + key) * 1536 + 1024 + h * HD + dc);
    }
    __syncthreads();
    {
        const int d = t & 31, kc = (t >> 5) * 8;
        bf16x8 v;
        #pragma unroll
        for (int i = 0; i < 8; i++) v[i] = (short)tile[kc + i][d];
        *(bf16x8*)(vt + (((long)(b * NH + h)) * HD + d) * N_TOK + k0 + kc) = v;
    }
}

// ---------------- Token path v4: 1024 blocks, 8 waves = 2 qs x 4 key-quarters
// Block covers 64 q rows; wave (qs,kq) does q-subtile qs over keys
// [kq*512, kq*512+512). LDS: P (32KB) unioned with epilogue comb+Ot.
__global__ __launch_bounds__(512) void attn_x4(
    const u16* __restrict__ qkv, const u16* __restrict__ vt,
    u16* __restrict__ aob)
{
    const int b = blockIdx.z, h = blockIdx.y;
    const int wid = threadIdx.x >> 6, lane = threadIdx.x & 63;
    const int lr = lane & 15, lg = lane >> 4;
    const int qs = wid & 1, kq = wid >> 1;
    const int q0 = blockIdx.x * 64 + qs * 32;

    __shared__ __align__(16) char smem[32768];
    unsigned int (*Pw)[32] = (unsigned int (*)[32])(smem + wid * 4096); // [32][32] u32
    float* combB = (float*)smem;                 // [6][64][18] f32 = 27648 B
    u16*   OtB   = (u16*)(smem + 27648);         // [2][32][40] u16 =  5120 B

    const int sw = 4 * (lr & 7);                 // swizzle: col ^= 4*(qrow&7)

    bf16x8 qf[2];
    #pragma unroll
    for (int qq = 0; qq < 2; qq++)
        qf[qq] = *(const bf16x8*)(
            qkv + ((long)b * N_TOK + q0 + qq * 16 + lr) * 1536 + h * HD + lg * 8);

    f32x4 o[2][2] = {};
    float rs[2] = {0.f, 0.f};
    const u16* kbase = qkv + (long)b * N_TOK * 1536 + 512 + h * HD + lg * 8;
    const u16* vbase = vt + ((long)(b * NH + h)) * HD * N_TOK;

    const int kstart = kq * 512;
    for (int k0 = kstart; k0 < kstart + 512; k0 += 64) {
        bf16x8 kf[4];
        #pragma unroll
        for (int kg = 0; kg < 4; kg++)
            kf[kg] = *(const bf16x8*)(kbase + (long)(k0 + kg * 16 + lr) * 1536);
        #pragma unroll
        for (int qq = 0; qq < 2; qq++) {
            #pragma unroll
            for (int kg = 0; kg < 4; kg++) {
                f32x4 z = {0.f, 0.f, 0.f, 0.f};
                f32x4 s = __builtin_amdgcn_mfma_f32_16x16x32_bf16(kf[kg], qf[qq], z, 0, 0, 0);
                float e0 = EXP2(s[0]), e1 = EXP2(s[1]);
                float e2 = EXP2(s[2]), e3 = EXP2(s[3]);
                rs[qq] += (e0 + e1) + (e2 + e3);
                uint2 w = { cvt_pk_bf16(e0, e1), cvt_pk_bf16(e2, e3) };
                *(uint2*)&Pw[qq * 16 + lr][(kg * 8 + lg * 2) ^ sw] = w;
            }
        }
        #pragma unroll
        for (int c = 0; c < 2; c++) {
            bf16x8 pb0 = *(const bf16x8*)&Pw[lr][(c * 16 + lg * 4) ^ sw];
            bf16x8 pb1 = *(const bf16x8*)&Pw[16 + lr][(c * 16 + lg * 4) ^ sw];
            #pragma unroll
            for (int dg = 0; dg < 2; dg++) {
                bf16x8 vf = *(const bf16x8*)(
                    vbase + (long)(dg * 16 + lr) * N_TOK + k0 + c * 32 + lg * 8);
                o[0][dg] = __builtin_amdgcn_mfma_f32_16x16x32_bf16(vf, pb0, o[0][dg], 0, 0, 0);
                o[1][dg] = __builtin_amdgcn_mfma_f32_16x16x32_bf16(vf, pb1, o[1][dg], 0, 0, 0);
            }
        }
    }
    #pragma unroll
    for (int qq = 0; qq < 2; qq++) {
        rs[qq] += __shfl_xor(rs[qq], 16);
        rs[qq] += __shfl_xor(rs[qq], 32);
    }
    __syncthreads();                     // all waves done with P before aliasing
    if (kq > 0) {
        float* cp = combB + (((qs * 3 + kq - 1) * 64) + lane) * 18;
        #pragma unroll
        for (int qq = 0; qq < 2; qq++)
            #pragma unroll
            for (int dg = 0; dg < 2; dg++)
                #pragma unroll
                for (int r = 0; r < 4; r++)
                    cp[qq * 8 + dg * 4 + r] = o[qq][dg][r];
        cp[16] = rs[0];
        cp[17] = rs[1];
    }
    __syncthreads();
    if (kq == 0) {
        #pragma unroll
        for (int j = 0; j < 3; j++) {
            const float* cp = combB + (((qs * 3 + j) * 64) + lane) * 18;
            #pragma unroll
            for (int qq = 0; qq < 2; qq++)
                #pragma unroll
                for (int dg = 0; dg < 2; dg++)
                    #pragma unroll
                    for (int r = 0; r < 4; r++)
                        o[qq][dg][r] += cp[qq * 8 + dg * 4 + r];
            rs[0] += cp[16];
            rs[1] += cp[17];
        }
        const float inv0 = 1.f / rs[0], inv1 = 1.f / rs[1];
        u16* Ot = OtB + qs * 32 * 40;    // [32 q][40 pad]
        #pragma unroll
        for (int dg = 0; dg < 2; dg++)
            #pragma unroll
            for (int r = 0; r < 4; r++) {
                Ot[lr * 40 + dg * 16 + lg * 4 + r]        = f2b(o[0][dg][r] * inv0);
                Ot[(16 + lr) * 40 + dg * 16 + lg * 4 + r] = f2b(o[1][dg][r] * inv1);
            }
        const int rrow = lane >> 2, seg = lane & 3;
        #pragma unroll
        for (int rep = 0; rep < 2; rep++) {
            bf16x8 v = *(const bf16x8*)&Ot[(rep * 16 + rrow) * 40 + seg * 8];
            *(bf16x8*)(aob + ((long)b * N_ALL + q0 + rep * 16 + rrow) * DMODEL + h * HD + seg * 8) = v;
        }
    }
}

// ---------------- Cluster path: 8 waves x 32 clusters, fused colsum + PV -----
// grid (8,16,2), 512 thr. Block covers 256 keys (key-split 8 across blocks).
__global__ __launch_bounds__(512) void attn_c_mfma(
    const u16* __restrict__ qc, const u16* __restrict__ qkv,
    const u16* __restrict__ vt, float* __restrict__ part)
{
    const int b = blockIdx.z, h = blockIdx.y, kblk = blockIdx.x;
    const int wid = threadIdx.x >> 6, lane = threadIdx.x & 63;
    const int lr = lane & 15, lg = lane >> 4;
    const int c0 = wid * 32;

    __shared__ u16 Pl[8][32][72];     // 36864 B
    __shared__ float cs2[64][8];      //  2048 B
    u16 (*P)[72] = Pl[wid];

    bf16x8 qf[2];
    #pragma unroll
    for (int qs = 0; qs < 2; qs++)
        qf[qs] = *(const bf16x8*)(
            qc + ((long)(b * N_CLU) + c0 + qs * 16 + lr) * DMODEL + h * HD + lg * 8);

    f32x4 o[2][2] = {};
    float rs[2][4] = {};
    const u16* kbase = qkv + (long)b * N_TOK * 1536 + 512 + h * HD + lg * 8;
    const u16* vbase = vt + ((long)(b * NH + h)) * HD * N_TOK;

    for (int kt = 0; kt < 4; kt++) {
        const int k0 = kblk * 256 + kt * 64;
        bf16x8 kf[4];
        #pragma unroll
        for (int kg = 0; kg < 4; kg++)
            kf[kg] = *(const bf16x8*)(kbase + (long)(k0 + kg * 16 + lr) * 1536);
        f32x4 e[2][4];
        #pragma unroll
        for (int qs = 0; qs < 2; qs++)
            #pragma unroll
            for (int kg = 0; kg < 4; kg++) {
                f32x4 z = {0.f, 0.f, 0.f, 0.f};
                e[qs][kg] = __builtin_amdgcn_mfma_f32_16x16x32_bf16(qf[qs], kf[kg], z, 0, 0, 0);
            }
        float csum[4];
        #pragma unroll
        for (int kg = 0; kg < 4; kg++) {
            float v = 0.f;
            #pragma unroll
            for (int qs = 0; qs < 2; qs++)
                #pragma unroll
                for (int r = 0; r < 4; r++) {
                    float p = EXP2(e[qs][kg][r]);     // qc pre-scaled by log2e
                    e[qs][kg][r] = p;
                    v += p;
                }
            v += __shfl_xor(v, 16);
            v += __shfl_xor(v, 32);
            csum[kg] = v;                // key kg*16+lr, this wave's 32 clusters
        }
        float own = (lg == 0) ? csum[0] : (lg == 1) ? csum[1] : (lg == 2) ? csum[2] : csum[3];
        __syncthreads();                 // prior-iter cs2 reads complete
        cs2[lane][wid] = own;
        __syncthreads();
        float ics[4];
        #pragma unroll
        for (int kg = 0; kg < 4; kg++) {
            f32x4 a = *(const f32x4*)&cs2[kg * 16 + lr][0];
            f32x4 c = *(const f32x4*)&cs2[kg * 16 + lr][4];
            ics[kg] = 1.f / ((a[0] + a[1] + a[2] + a[3]) + (c[0] + c[1] + c[2] + c[3]));
        }
        #pragma unroll
        for (int qs = 0; qs < 2; qs++)
            #pragma unroll
            for (int kg = 0; kg < 4; kg++) {
                #pragma unroll
                for (int r = 0; r < 4; r++) {
                    float p = e[qs][kg][r] * ics[kg];
                    rs[qs][r] += p;
                    P[qs * 16 + lg * 4 + r][kg * 16 + lr] = f2b(p);
                }
            }
        #pragma unroll
        for (int kh = 0; kh < 2; kh++) {
            bf16x8 pf[2];
            #pragma unroll
            for (int qs = 0; qs < 2; qs++)
                pf[qs] = *(const bf16x8*)&P[qs * 16 + lr][kh * 32 + lg * 8];
            #pragma unroll
            for (int dg = 0; dg < 2; dg++) {
                bf16x8 vf = *(const bf16x8*)(
                    vbase + (long)(dg * 16 + lr) * N_TOK + k0 + kh * 32 + lg * 8);
                #pragma unroll
                for (int qs = 0; qs < 2; qs++)
                    o[qs][dg] = __builtin_amdgcn_mfma_f32_16x16x32_bf16(pf[qs], vf, o[qs][dg], 0, 0, 0);
            }
        }
    }
    float* pp = part + ((((long)(b * NH + h)) * 8 + kblk) * 256) * 36;
    #pragma unroll
    for (int qs = 0; qs < 2; qs++)
        #pragma unroll
        for (int r = 0; r < 4; r++) {
            const int row = c0 + qs * 16 + lg * 4 + r;
            pp[(long)row * 36 + lr]      = o[qs][0][r];
            pp[(long)row * 36 + 16 + lr] = o[qs][1][r];
            float v = rs[qs][r];
            v += __shfl_xor(v, 1); v += __shfl_xor(v, 2);
            v += __shfl_xor(v, 4); v += __shfl_xor(v, 8);
            if (lr == 0) pp[(long)row * 36 + 32] = v;
        }
}

// ---------------- Cluster partial reduce (bf16 out) --------------------------
__global__ __launch_bounds__(256) void attn_c_reduce(
    const float* __restrict__ part, u16* __restrict__ aob)
{
    const int gid = blockIdx.x * 256 + threadIdx.x;   // 8192
    const int b = gid >> 12, h = (gid >> 8) & 15, c = gid & 255;
    float acc[32] = {};
    float rsum = 0.f;
    for (int j = 0; j < 8; j++) {
        const float* pp = part + ((((long)(b * NH + h)) * 8 + j) * 256 + c) * 36;
        #pragma unroll
        for (int e4 = 0; e4 < 8; e4++) {
            f32x4 v = *(const f32x4*)(pp + e4 * 4);
            acc[e4 * 4 + 0] += v[0]; acc[e4 * 4 + 1] += v[1];
            acc[e4 * 4 + 2] += v[2]; acc[e4 * 4 + 3] += v[3];
        }
        rsum += pp[32];
    }
    const float inv = 1.f / (rsum + 1e-5f);
    u16* orow = aob + ((long)b * N_ALL + N_TOK + c) * DMODEL + h * HD;
    #pragma unroll
    for (int e = 0; e < 32; e++) orow[e] = f2b(acc[e] * inv);
}

extern "C" void kernel_launch(void* const* d_in, const int* in_sizes, int n_in,
                              void* d_out, int out_size, void* d_ws, size_t ws_size,
                              hipStream_t stream)
{
    const float* x        = (const float*)d_in[0];
    const float* clusters = (const float*)d_in[1];
    // d_in[2] token_sizes: dead input (softmax-shift-invariant)
    const float* Wq  = (const float*)d_in[3];
    const float* Wkv = (const float*)d_in[4];
    const float* Wo  = (const float*)d_in[5];
    float* out = (float*)d_out;

    char* ws = (char*)d_ws;
    u16*   xb    = (u16*)(ws);                    //  4,194,304
    u16*   cb    = (u16*)(ws + 4194304);          //    524,288
    u16*   WcatT = (u16*)(ws + 4718592);          //  1,572,864  [1536][512]
    u16*   WoT   = (u16*)(ws + 6291456);          //    524,288
    u16*   qkv   = (u16*)(ws + 6815744);          // 12,582,912  [2][2048][1536]
    u16*   qc    = (u16*)(ws + 19398656);         //    524,288  [2][256][512]
    u16*   vt    = (u16*)(ws + 19922944);         //  4,194,304
    u16*   aob   = (u16*)(ws + 24117248);         //  4,718,592
    float* part  = (float*)(ws + 28835840);       //  9,437,184  (end 38,273,024)

    // input conversions (log2e*scale folded into Wq)
    cvt_bf16_k<<<dim3(1024), 256, 0, stream>>>(x, xb);
    cvt_bf16_k<<<dim3(128),  256, 0, stream>>>(clusters, cb);
    cvtT_k<<<dim3(16, 16), 256, 0, stream>>>(Wq,  WcatT,             512,  512, EXPSCALE);
    cvtT_k<<<dim3(32, 16), 256, 0, stream>>>(Wkv, WcatT + 512 * 512, 512, 1024, 1.f);
    cvtT_k<<<dim3(16, 16), 256, 0, stream>>>(Wo,  WoT,               512,  512, 1.f);

    // fused q|k|v projection: qkv = x @ [Wq*s | Wkv]   (N = 1536)
    gemm_bf16<<<dim3(12, 16, 2), 256, 0, stream>>>(
        xb, (long)N_TOK * DMODEL, WcatT, qkv, (long)N_TOK * 1536, 1536, DMODEL, 0);
    // cluster q projection (N = 512)
    gemm_bf16<<<dim3(4, 2, 2), 256, 0, stream>>>(
        cb, (long)N_CLU * DMODEL, WcatT, qc, (long)N_CLU * DMODEL, DMODEL, DMODEL, 0);

    vt_prep<<<dim3(32, 16, 2), 256, 0, stream>>>(qkv, vt);

    attn_x4<<<dim3(32, 16, 2), 512, 0, stream>>>(qkv, vt, aob);
    attn_c_mfma<<<dim3(8, 16, 2), 512, 0, stream>>>(qc, qkv, vt, part);
    attn_c_reduce<<<dim3(32), 256, 0, stream>>>(part, aob);

    // merged output projection: [aob 4608x512] @ Wo -> out (row-remapped)
    gemm_bf16<<<dim3(4, 36, 1), 256, 0, stream>>>(
        aob, 0, WoT, out, 0, DMODEL, DMODEL, 1);
}